// Round 3
// baseline (532.008 us; speedup 1.0000x reference)
//
#include <hip/hip_runtime.h>

// ---------------- problem constants ----------------
#define BATCH 4
#define SEQ 2048
#define DM 1024
#define NH 16
#define SCALE 0.125f   // 64^-0.5

typedef unsigned short ushort_t;
typedef short bf16x8 __attribute__((ext_vector_type(8)));
typedef float f32x4 __attribute__((ext_vector_type(4)));

__device__ __forceinline__ ushort_t f2bf(float f) {
    unsigned u = __float_as_uint(f);
    unsigned r = (u + 0x7FFFu + ((u >> 16) & 1u)) >> 16;
    return (ushort_t)r;
}

__device__ __forceinline__ void glds16(const ushort_t* g, ushort_t* l) {
    __builtin_amdgcn_global_load_lds(
        (const __attribute__((address_space(1))) unsigned*)g,
        (__attribute__((address_space(3))) unsigned*)l, 16, 0, 0);
}

// ---------------- cast x: f32 -> bf16, 4 elems/thread ----------------
__global__ void cast_f32_bf16(const float* __restrict__ in, ushort_t* __restrict__ out, int n) {
    int i = (blockIdx.x * blockDim.x + threadIdx.x) * 4;
    if (i < n) {
        float4 v = *(const float4*)(in + i);
        ushort4 o;
        o.x = f2bf(v.x); o.y = f2bf(v.y); o.z = f2bf(v.z); o.w = f2bf(v.w);
        *(ushort4*)(out + i) = o;
    }
}

// ---------------- transpose+cast: in[K][N] f32 -> out[N][K] bf16 ----------------
__global__ void transpose_cast(const float* __restrict__ in, ushort_t* __restrict__ out,
                               int K, int N) {
    __shared__ float tile[32][33];
    int n0 = blockIdx.x * 32, k0 = blockIdx.y * 32;
    int x = threadIdx.x, y = threadIdx.y;   // blockDim = (32, 8)
#pragma unroll
    for (int j = 0; j < 32; j += 8)
        tile[y + j][x] = in[(size_t)(k0 + y + j) * N + n0 + x];
    __syncthreads();
#pragma unroll
    for (int j = 0; j < 32; j += 8)
        out[(size_t)(n0 + y + j) * K + k0 + x] = f2bf(tile[x][y + j]);
}

// ---------------- GEMM: C[M][N] = A[M][K] @ Bt[N][K]^T + bias[N] ----------------
// m97-class: 128x128 tile, 4 waves (2x2), BK=64, global_load_lds width=16 into
// linear [128][64] LDS with XOR chunk swizzle (pre-swizzled global source +
// swizzled ds_read_b128) -> 2-way max bank aliasing. 32 MFMA per barrier pair.
template <bool OUT_F32>
__global__ __launch_bounds__(256) void gemm_abt(
    const ushort_t* __restrict__ A, const ushort_t* __restrict__ Bt,
    const float* __restrict__ bias, void* __restrict__ Cout,
    int M, int N, int K) {
    __shared__ __attribute__((aligned(16))) ushort_t As[128 * 64];
    __shared__ __attribute__((aligned(16))) ushort_t Bs[128 * 64];
    const int tid = threadIdx.x;
    const int lane = tid & 63, wave = tid >> 6;
    const int l15 = lane & 15, l4 = lane >> 4;
    const int m0 = blockIdx.y * 128, n0 = blockIdx.x * 128;
    const int wr = (wave >> 1) * 64, wc = (wave & 1) * 64;
    // staging: wave w stages rows w*32..w*32+31 (4 calls of 8 rows).
    // source chunk pre-swizzled: kch = (lane&7) ^ (row&7)
    const int r8 = lane >> 3;                 // row offset within 8-row group
    const int kch = (lane & 7) ^ r8;
    const ushort_t* gA = A + (size_t)(m0 + wave * 32 + r8) * K + kch * 8;
    const ushort_t* gB = Bt + (size_t)(n0 + wave * 32 + r8) * K + kch * 8;
    const int r7 = l15 & 7;                   // row&7 for all frag reads

    f32x4 acc[4][4];
#pragma unroll
    for (int i = 0; i < 4; ++i)
#pragma unroll
        for (int j = 0; j < 4; ++j) acc[i][j] = (f32x4){0.f, 0.f, 0.f, 0.f};

    for (int k0 = 0; k0 < K; k0 += 64) {
#pragma unroll
        for (int c = 0; c < 4; ++c) {
            glds16(gA + k0 + (size_t)(c * 8) * K, &As[(wave * 32 + c * 8) * 64]);
            glds16(gB + k0 + (size_t)(c * 8) * K, &Bs[(wave * 32 + c * 8) * 64]);
        }
        __syncthreads();
#pragma unroll
        for (int kh = 0; kh < 2; ++kh) {
            const int ch = ((kh * 4 + l4) ^ r7) * 8;
            bf16x8 a[4], b[4];
#pragma unroll
            for (int i = 0; i < 4; ++i) {
                a[i] = *(const bf16x8*)&As[(wr + i * 16 + l15) * 64 + ch];
                b[i] = *(const bf16x8*)&Bs[(wc + i * 16 + l15) * 64 + ch];
            }
#pragma unroll
            for (int mi = 0; mi < 4; ++mi)
#pragma unroll
                for (int ni = 0; ni < 4; ++ni)
                    acc[mi][ni] = __builtin_amdgcn_mfma_f32_16x16x32_bf16(
                        a[mi], b[ni], acc[mi][ni], 0, 0, 0);
        }
        __syncthreads();
    }

#pragma unroll
    for (int mi = 0; mi < 4; ++mi)
#pragma unroll
        for (int ni = 0; ni < 4; ++ni)
#pragma unroll
            for (int r = 0; r < 4; ++r) {
                int row = m0 + wr + mi * 16 + l4 * 4 + r;
                int col = n0 + wc + ni * 16 + l15;
                float v = acc[mi][ni][r] + bias[col];
                if (OUT_F32)
                    ((float*)Cout)[(size_t)row * N + col] = v;
                else
                    ((ushort_t*)Cout)[(size_t)row * N + col] = f2bf(v);
            }
}

// ---------------- flash attention ----------------
// Complementary-pair scheduling: block (bh, pair) handles q-blocks bqH=31-pair
// and bqL=pair, sharing staged K/V tiles. Per-block work = 33 wave-tile-units
// for EVERY block -> balanced, 1024 blocks = 4/CU all resident (LDS 40960 B).
// K/V double-buffered; K via global_load_lds (pre-swizzled source), V reg-
// staged transposed (issue loads early, scatter after compute = T14 split).
struct AState {
    bf16x8 q0, q1;
    f32x4 o[4];
    float m, l;
};

__device__ __forceinline__ void attn_init(AState& S, const ushort_t* qkv, size_t rowbase,
                                          int qbase, int h, int l15, int l4) {
    const ushort_t* qp = qkv + (rowbase + qbase + l15) * 3072 + h * 64 + l4 * 8;
    S.q0 = *(const bf16x8*)qp;
    S.q1 = *(const bf16x8*)(qp + 32);
#pragma unroll
    for (int i = 0; i < 4; ++i) S.o[i] = (f32x4){0.f, 0.f, 0.f, 0.f};
    S.m = -INFINITY;
    S.l = 0.f;
}

__device__ __forceinline__ void scatterV(ushort_t* V, bf16x8 v0, bf16x8 v1, int key, int d0) {
#pragma unroll
    for (int j = 0; j < 8; ++j) {
        int d = d0 + j;
        V[d * 64 + (key ^ ((d & 7) << 3))] = (ushort_t)v0[j];
        int d2 = d0 + 8 + j;
        V[d2 * 64 + (key ^ ((d2 & 7) << 3))] = (ushort_t)v1[j];
    }
}

__device__ __forceinline__ void attn_tile(AState& S, const ushort_t* __restrict__ Ks,
                                          const ushort_t* __restrict__ Vt,
                                          ushort_t* __restrict__ Plw,
                                          int l15, int l4, int rel) {
    // QK^T (swapped): S^T[key][q], key=(l4*4+r)+16*kt, q=l15
    float p[16];
    float pmax = -INFINITY;
#pragma unroll
    for (int kt = 0; kt < 4; ++kt) {
        const int row = kt * 16 + l15, r7 = row & 7;
        bf16x8 ak0 = *(const bf16x8*)&Ks[row * 64 + ((l4 ^ r7) * 8)];
        bf16x8 ak1 = *(const bf16x8*)&Ks[row * 64 + (((4 + l4) ^ r7) * 8)];
        f32x4 z = {0.f, 0.f, 0.f, 0.f};
        z = __builtin_amdgcn_mfma_f32_16x16x32_bf16(ak0, S.q0, z, 0, 0, 0);
        z = __builtin_amdgcn_mfma_f32_16x16x32_bf16(ak1, S.q1, z, 0, 0, 0);
#pragma unroll
        for (int r = 0; r < 4; ++r) {
            float v = z[r] * SCALE;
            v = (kt * 16 + l4 * 4 + r > rel) ? -INFINITY : v;
            p[kt * 4 + r] = v;
            pmax = fmaxf(pmax, v);
        }
    }
    pmax = fmaxf(pmax, __shfl_xor(pmax, 16));
    pmax = fmaxf(pmax, __shfl_xor(pmax, 32));
    const float m_new = fmaxf(S.m, pmax);
    const float scl = __expf(S.m - m_new);     // 0 on first tile
    float rsum = 0.f;
#pragma unroll
    for (int i = 0; i < 16; ++i) { p[i] = __expf(p[i] - m_new); rsum += p[i]; }
    rsum += __shfl_xor(rsum, 16);
    rsum += __shfl_xor(rsum, 32);
    S.l = S.l * scl + rsum;
    S.m = m_new;

    // P -> LDS (swizzled), row q=l15
    const int pr7 = l15 & 7;
#pragma unroll
    for (int kt = 0; kt < 4; ++kt) {
        ushort4 pk;
        pk.x = f2bf(p[kt * 4 + 0]);
        pk.y = f2bf(p[kt * 4 + 1]);
        pk.z = f2bf(p[kt * 4 + 2]);
        pk.w = f2bf(p[kt * 4 + 3]);
        *(ushort4*)&Plw[l15 * 64 + ((kt * 16 + l4 * 4) ^ (pr7 << 3))] = pk;
    }

    // rescale O (rows q = l4*4+r)
    const float sc0 = __shfl(scl, l4 * 4 + 0);
    const float sc1 = __shfl(scl, l4 * 4 + 1);
    const float sc2 = __shfl(scl, l4 * 4 + 2);
    const float sc3 = __shfl(scl, l4 * 4 + 3);
#pragma unroll
    for (int dt = 0; dt < 4; ++dt) {
        S.o[dt][0] *= sc0; S.o[dt][1] *= sc1; S.o[dt][2] *= sc2; S.o[dt][3] *= sc3;
    }

    // PV
    bf16x8 pa0 = *(const bf16x8*)&Plw[l15 * 64 + ((l4 ^ pr7) * 8)];
    bf16x8 pa1 = *(const bf16x8*)&Plw[l15 * 64 + (((4 + l4) ^ pr7) * 8)];
#pragma unroll
    for (int dt = 0; dt < 4; ++dt) {
        const int d = dt * 16 + l15, r7 = d & 7;
        bf16x8 bv0 = *(const bf16x8*)&Vt[d * 64 + ((l4 ^ r7) * 8)];
        bf16x8 bv1 = *(const bf16x8*)&Vt[d * 64 + (((4 + l4) ^ r7) * 8)];
        S.o[dt] = __builtin_amdgcn_mfma_f32_16x16x32_bf16(pa0, bv0, S.o[dt], 0, 0, 0);
        S.o[dt] = __builtin_amdgcn_mfma_f32_16x16x32_bf16(pa1, bv1, S.o[dt], 0, 0, 0);
    }
}

__device__ __forceinline__ void attn_store(const AState& S, ushort_t* out, size_t rowbase,
                                           int qbase, int h, int l15, int l4) {
    const float li0 = __shfl(S.l, l4 * 4 + 0);
    const float li1 = __shfl(S.l, l4 * 4 + 1);
    const float li2 = __shfl(S.l, l4 * 4 + 2);
    const float li3 = __shfl(S.l, l4 * 4 + 3);
#pragma unroll
    for (int r = 0; r < 4; ++r) {
        const int qr = qbase + l4 * 4 + r;
        const float li = (r == 0) ? li0 : (r == 1) ? li1 : (r == 2) ? li2 : li3;
        ushort_t* op = out + (rowbase + qr) * DM + h * 64 + l15;
#pragma unroll
        for (int dt = 0; dt < 4; ++dt)
            op[dt * 16] = f2bf(S.o[dt][r] / li);
    }
}

__global__ __launch_bounds__(256, 4) void attn_kernel(const ushort_t* __restrict__ qkv,
                                                      ushort_t* __restrict__ out) {
    __shared__ __attribute__((aligned(16))) ushort_t Ks[2][64 * 64];
    __shared__ __attribute__((aligned(16))) ushort_t Vt[2][64 * 64];
    __shared__ __attribute__((aligned(16))) ushort_t Pl[4][16 * 64];
    const int tid = threadIdx.x;
    const int wave = tid >> 6, lane = tid & 63;
    const int l15 = lane & 15, l4 = lane >> 4;
    const int bh = blockIdx.x;                  // 0..63
    const int b = bh >> 4, h = bh & 15;
    const int pair = blockIdx.y;                // 0..15
    const int bqH = 31 - pair, bqL = pair;
    const int ntH = bqH + 1, ntL = bqL + 1;
    const size_t rowbase = (size_t)b * SEQ;
    const int qbH = bqH * 64 + wave * 16;
    const int qbL = bqL * 64 + wave * 16;

    AState SH, SL;
    attn_init(SH, qkv, rowbase, qbH, h, l15, l4);
    attn_init(SL, qkv, rowbase, qbL, h, l15, l4);

    // staging lane geometry
    const int krow = lane >> 3;                 // 0..7
    const int kch = (lane & 7) ^ krow;          // pre-swizzled source chunk
    const int sv_key = tid & 63, sv_d0 = (tid >> 6) * 16;

    // ---- prologue: stage tile 0 into buffer 0 ----
    {
        const ushort_t* gk = qkv + (rowbase + wave * 16 + krow) * 3072 + 1024 + h * 64 + kch * 8;
        glds16(gk, &Ks[0][(wave * 16) * 64]);
        glds16(gk + (size_t)8 * 3072, &Ks[0][(wave * 16 + 8) * 64]);
        const ushort_t* gv = qkv + (rowbase + sv_key) * 3072 + 2048 + h * 64 + sv_d0;
        bf16x8 v0 = *(const bf16x8*)gv;
        bf16x8 v1 = *(const bf16x8*)(gv + 8);
        scatterV(Vt[0], v0, v1, sv_key, sv_d0);
    }
    __syncthreads();   // drains vmcnt+lgkm: tile 0 staged

    for (int t = 0; t < ntH; ++t) {
        const int db = t & 1;
        const bool more = (t + 1 < ntH);
        bf16x8 nv0, nv1;
        if (more) {
            const int kb = (t + 1) * 64;
            const ushort_t* gk = qkv + (rowbase + kb + wave * 16 + krow) * 3072
                                 + 1024 + h * 64 + kch * 8;
            glds16(gk, &Ks[db ^ 1][(wave * 16) * 64]);
            glds16(gk + (size_t)8 * 3072, &Ks[db ^ 1][(wave * 16 + 8) * 64]);
            const ushort_t* gv = qkv + (rowbase + kb + sv_key) * 3072 + 2048 + h * 64 + sv_d0;
            nv0 = *(const bf16x8*)gv;
            nv1 = *(const bf16x8*)(gv + 8);
        }
        const int kbase = t * 64;
        attn_tile(SH, Ks[db], Vt[db], Pl[wave], l15, l4, qbH + l15 - kbase);
        if (t < ntL)
            attn_tile(SL, Ks[db], Vt[db], Pl[wave], l15, l4, qbL + l15 - kbase);
        if (more)
            scatterV(Vt[db ^ 1], nv0, nv1, sv_key, sv_d0);
        __syncthreads();   // next buffer fully staged; current free for reuse
    }

    attn_store(SH, out, rowbase, qbH, h, l15, l4);
    attn_store(SL, out, rowbase, qbL, h, l15, l4);
}

// ---------------- launcher ----------------
extern "C" void kernel_launch(void* const* d_in, const int* in_sizes, int n_in,
                              void* d_out, int out_size, void* d_ws, size_t ws_size,
                              hipStream_t stream) {
    const float* x     = (const float*)d_in[0];
    // d_in[1] = mask (causal, implemented analytically)
    const float* W_qkv = (const float*)d_in[2];
    const float* b_qkv = (const float*)d_in[3];
    const float* W_out = (const float*)d_in[4];
    const float* b_out = (const float*)d_in[5];
    float* out = (float*)d_out;

    char* ws = (char*)d_ws;
    ushort_t* xb    = (ushort_t*)(ws);                      // 16,777,216 B
    ushort_t* WqkvT = (ushort_t*)(ws + 16777216);           //  6,291,456 B
    ushort_t* WoutT = (ushort_t*)(ws + 23068672);           //  2,097,152 B
    ushort_t* qkv   = (ushort_t*)(ws + 25165824);           // 50,331,648 B
    ushort_t* attn  = (ushort_t*)(ws + 75497472);           // 16,777,216 B

    const int nx = BATCH * SEQ * DM;                        // 8,388,608
    cast_f32_bf16<<<nx / (256 * 4), 256, 0, stream>>>(x, xb, nx);
    transpose_cast<<<dim3(3 * DM / 32, DM / 32), dim3(32, 8), 0, stream>>>(W_qkv, WqkvT, DM, 3 * DM);
    transpose_cast<<<dim3(DM / 32, DM / 32), dim3(32, 8), 0, stream>>>(W_out, WoutT, DM, DM);

    // QKV projection: [8192,1024] @ [1024,3072] -> bf16 qkv
    gemm_abt<false><<<dim3(3 * DM / 128, BATCH * SEQ / 128), 256, 0, stream>>>(
        xb, WqkvT, b_qkv, qkv, BATCH * SEQ, 3 * DM, DM);

    // attention: complementary-pair blocks
    attn_kernel<<<dim3(BATCH * NH, SEQ / 128), 256, 0, stream>>>(qkv, attn);

    // output projection: [8192,1024] @ [1024,1024] -> f32 out
    gemm_abt<true><<<dim3(DM / 128, BATCH * SEQ / 128), 256, 0, stream>>>(
        attn, WoutT, b_out, out, BATCH * SEQ, DM, DM);
}

// Round 4
// 357.302 us; speedup vs baseline: 1.4890x; 1.4890x over previous
//
#include <hip/hip_runtime.h>

// ---------------- problem constants ----------------
#define BATCH 4
#define SEQ 2048
#define DM 1024
#define NH 16
#define SCALE 0.125f   // 64^-0.5

typedef unsigned short ushort_t;
typedef short bf16x8 __attribute__((ext_vector_type(8)));
typedef float f32x4 __attribute__((ext_vector_type(4)));

__device__ __forceinline__ ushort_t f2bf(float f) {
    unsigned u = __float_as_uint(f);
    unsigned r = (u + 0x7FFFu + ((u >> 16) & 1u)) >> 16;
    return (ushort_t)r;
}

__device__ __forceinline__ void glds16(const ushort_t* g, ushort_t* l) {
    __builtin_amdgcn_global_load_lds(
        (const __attribute__((address_space(1))) unsigned*)g,
        (__attribute__((address_space(3))) unsigned*)l, 16, 0, 0);
}

// ---------------- cast x: f32 -> bf16, 4 elems/thread ----------------
__global__ void cast_f32_bf16(const float* __restrict__ in, ushort_t* __restrict__ out, int n) {
    int i = (blockIdx.x * blockDim.x + threadIdx.x) * 4;
    if (i < n) {
        float4 v = *(const float4*)(in + i);
        ushort4 o;
        o.x = f2bf(v.x); o.y = f2bf(v.y); o.z = f2bf(v.z); o.w = f2bf(v.w);
        *(ushort4*)(out + i) = o;
    }
}

// ---------------- transpose+cast: in[K][N] f32 -> out[N][K] bf16 ----------------
__global__ void transpose_cast(const float* __restrict__ in, ushort_t* __restrict__ out,
                               int K, int N) {
    __shared__ float tile[32][33];
    int n0 = blockIdx.x * 32, k0 = blockIdx.y * 32;
    int x = threadIdx.x, y = threadIdx.y;   // blockDim = (32, 8)
#pragma unroll
    for (int j = 0; j < 32; j += 8)
        tile[y + j][x] = in[(size_t)(k0 + y + j) * N + n0 + x];
    __syncthreads();
#pragma unroll
    for (int j = 0; j < 32; j += 8)
        out[(size_t)(n0 + y + j) * K + k0 + x] = f2bf(tile[x][y + j]);
}

// ---------------- GEMM: C[M][N] = A[M][K] @ Bt[N][K]^T + bias[N] ----------------
// 128x128 tile, 4 waves (2x2), BK=64, global_load_lds width=16 into linear
// [128][64] LDS with XOR chunk swizzle. 32 MFMA per barrier pair.
template <bool OUT_F32>
__global__ __launch_bounds__(256) void gemm_abt(
    const ushort_t* __restrict__ A, const ushort_t* __restrict__ Bt,
    const float* __restrict__ bias, void* __restrict__ Cout,
    int M, int N, int K) {
    __shared__ __attribute__((aligned(16))) ushort_t As[128 * 64];
    __shared__ __attribute__((aligned(16))) ushort_t Bs[128 * 64];
    const int tid = threadIdx.x;
    const int lane = tid & 63, wave = tid >> 6;
    const int l15 = lane & 15, l4 = lane >> 4;
    const int m0 = blockIdx.y * 128, n0 = blockIdx.x * 128;
    const int wr = (wave >> 1) * 64, wc = (wave & 1) * 64;
    const int r8 = lane >> 3;
    const int kch = (lane & 7) ^ r8;
    const ushort_t* gA = A + (size_t)(m0 + wave * 32 + r8) * K + kch * 8;
    const ushort_t* gB = Bt + (size_t)(n0 + wave * 32 + r8) * K + kch * 8;
    const int r7 = l15 & 7;

    f32x4 acc[4][4];
#pragma unroll
    for (int i = 0; i < 4; ++i)
#pragma unroll
        for (int j = 0; j < 4; ++j) acc[i][j] = (f32x4){0.f, 0.f, 0.f, 0.f};

    for (int k0 = 0; k0 < K; k0 += 64) {
#pragma unroll
        for (int c = 0; c < 4; ++c) {
            glds16(gA + k0 + (size_t)(c * 8) * K, &As[(wave * 32 + c * 8) * 64]);
            glds16(gB + k0 + (size_t)(c * 8) * K, &Bs[(wave * 32 + c * 8) * 64]);
        }
        __syncthreads();
#pragma unroll
        for (int kh = 0; kh < 2; ++kh) {
            const int ch = ((kh * 4 + l4) ^ r7) * 8;
            bf16x8 a[4], b[4];
#pragma unroll
            for (int i = 0; i < 4; ++i) {
                a[i] = *(const bf16x8*)&As[(wr + i * 16 + l15) * 64 + ch];
                b[i] = *(const bf16x8*)&Bs[(wc + i * 16 + l15) * 64 + ch];
            }
#pragma unroll
            for (int mi = 0; mi < 4; ++mi)
#pragma unroll
                for (int ni = 0; ni < 4; ++ni)
                    acc[mi][ni] = __builtin_amdgcn_mfma_f32_16x16x32_bf16(
                        a[mi], b[ni], acc[mi][ni], 0, 0, 0);
        }
        __syncthreads();
    }

#pragma unroll
    for (int mi = 0; mi < 4; ++mi)
#pragma unroll
        for (int ni = 0; ni < 4; ++ni)
#pragma unroll
            for (int r = 0; r < 4; ++r) {
                int row = m0 + wr + mi * 16 + l4 * 4 + r;
                int col = n0 + wc + ni * 16 + l15;
                float v = acc[mi][ni][r] + bias[col];
                if (OUT_F32)
                    ((float*)Cout)[(size_t)row * N + col] = v;
                else
                    ((ushort_t*)Cout)[(size_t)row * N + col] = f2bf(v);
            }
}

// ---------------- flash attention ----------------
// Round-2 structure (single state per wave, 2048 blocks, heavy-first) +
// K/V double-buffer. K prefetch via global_load_lds issued BEFORE compute
// (drained by the end-of-tile barrier -> hides under compute); V prefetch
// as T14 split: vector load to regs early, swizzled scatter after compute.
// One barrier per tile. LDS 40 KB -> 4 blocks/CU.
struct AState {
    bf16x8 q0, q1;
    f32x4 o[4];
    float m, l;
};

__device__ __forceinline__ void attn_init(AState& S, const ushort_t* qkv, size_t rowbase,
                                          int qbase, int h, int l15, int l4) {
    const ushort_t* qp = qkv + (rowbase + qbase + l15) * 3072 + h * 64 + l4 * 8;
    S.q0 = *(const bf16x8*)qp;
    S.q1 = *(const bf16x8*)(qp + 32);
#pragma unroll
    for (int i = 0; i < 4; ++i) S.o[i] = (f32x4){0.f, 0.f, 0.f, 0.f};
    S.m = -INFINITY;
    S.l = 0.f;
}

__device__ __forceinline__ void scatterV(ushort_t* V, bf16x8 v0, bf16x8 v1, int key, int d0) {
#pragma unroll
    for (int j = 0; j < 8; ++j) {
        int d = d0 + j;
        V[d * 64 + (key ^ ((d & 7) << 3))] = (ushort_t)v0[j];
        int d2 = d0 + 8 + j;
        V[d2 * 64 + (key ^ ((d2 & 7) << 3))] = (ushort_t)v1[j];
    }
}

__device__ __forceinline__ void attn_tile(AState& S, const ushort_t* __restrict__ Ks,
                                          const ushort_t* __restrict__ Vt,
                                          ushort_t* __restrict__ Plw,
                                          int l15, int l4, int rel) {
    // QK^T (swapped): S^T[key][q], key=(l4*4+r)+16*kt, q=l15
    float p[16];
    float pmax = -INFINITY;
#pragma unroll
    for (int kt = 0; kt < 4; ++kt) {
        const int row = kt * 16 + l15, r7 = row & 7;
        bf16x8 ak0 = *(const bf16x8*)&Ks[row * 64 + ((l4 ^ r7) * 8)];
        bf16x8 ak1 = *(const bf16x8*)&Ks[row * 64 + (((4 + l4) ^ r7) * 8)];
        f32x4 z = {0.f, 0.f, 0.f, 0.f};
        z = __builtin_amdgcn_mfma_f32_16x16x32_bf16(ak0, S.q0, z, 0, 0, 0);
        z = __builtin_amdgcn_mfma_f32_16x16x32_bf16(ak1, S.q1, z, 0, 0, 0);
#pragma unroll
        for (int r = 0; r < 4; ++r) {
            float v = z[r] * SCALE;
            v = (kt * 16 + l4 * 4 + r > rel) ? -INFINITY : v;
            p[kt * 4 + r] = v;
            pmax = fmaxf(pmax, v);
        }
    }
    pmax = fmaxf(pmax, __shfl_xor(pmax, 16));
    pmax = fmaxf(pmax, __shfl_xor(pmax, 32));
    const float m_new = fmaxf(S.m, pmax);
    const float scl = __expf(S.m - m_new);     // 0 on first tile
    float rsum = 0.f;
#pragma unroll
    for (int i = 0; i < 16; ++i) { p[i] = __expf(p[i] - m_new); rsum += p[i]; }
    rsum += __shfl_xor(rsum, 16);
    rsum += __shfl_xor(rsum, 32);
    S.l = S.l * scl + rsum;
    S.m = m_new;

    // P -> LDS (swizzled), row q=l15
    const int pr7 = l15 & 7;
#pragma unroll
    for (int kt = 0; kt < 4; ++kt) {
        ushort4 pk;
        pk.x = f2bf(p[kt * 4 + 0]);
        pk.y = f2bf(p[kt * 4 + 1]);
        pk.z = f2bf(p[kt * 4 + 2]);
        pk.w = f2bf(p[kt * 4 + 3]);
        *(ushort4*)&Plw[l15 * 64 + ((kt * 16 + l4 * 4) ^ (pr7 << 3))] = pk;
    }

    // rescale O (rows q = l4*4+r)
    const float sc0 = __shfl(scl, l4 * 4 + 0);
    const float sc1 = __shfl(scl, l4 * 4 + 1);
    const float sc2 = __shfl(scl, l4 * 4 + 2);
    const float sc3 = __shfl(scl, l4 * 4 + 3);
#pragma unroll
    for (int dt = 0; dt < 4; ++dt) {
        S.o[dt][0] *= sc0; S.o[dt][1] *= sc1; S.o[dt][2] *= sc2; S.o[dt][3] *= sc3;
    }

    // PV
    bf16x8 pa0 = *(const bf16x8*)&Plw[l15 * 64 + ((l4 ^ pr7) * 8)];
    bf16x8 pa1 = *(const bf16x8*)&Plw[l15 * 64 + (((4 + l4) ^ pr7) * 8)];
#pragma unroll
    for (int dt = 0; dt < 4; ++dt) {
        const int d = dt * 16 + l15, r7 = d & 7;
        bf16x8 bv0 = *(const bf16x8*)&Vt[d * 64 + ((l4 ^ r7) * 8)];
        bf16x8 bv1 = *(const bf16x8*)&Vt[d * 64 + (((4 + l4) ^ r7) * 8)];
        S.o[dt] = __builtin_amdgcn_mfma_f32_16x16x32_bf16(pa0, bv0, S.o[dt], 0, 0, 0);
        S.o[dt] = __builtin_amdgcn_mfma_f32_16x16x32_bf16(pa1, bv1, S.o[dt], 0, 0, 0);
    }
}

__device__ __forceinline__ void attn_store(const AState& S, ushort_t* out, size_t rowbase,
                                           int qbase, int h, int l15, int l4) {
    const float li0 = __shfl(S.l, l4 * 4 + 0);
    const float li1 = __shfl(S.l, l4 * 4 + 1);
    const float li2 = __shfl(S.l, l4 * 4 + 2);
    const float li3 = __shfl(S.l, l4 * 4 + 3);
#pragma unroll
    for (int r = 0; r < 4; ++r) {
        const int qr = qbase + l4 * 4 + r;
        const float li = (r == 0) ? li0 : (r == 1) ? li1 : (r == 2) ? li2 : li3;
        ushort_t* op = out + (rowbase + qr) * DM + h * 64 + l15;
#pragma unroll
        for (int dt = 0; dt < 4; ++dt)
            op[dt * 16] = f2bf(S.o[dt][r] / li);
    }
}

__global__ __launch_bounds__(256, 4) void attn_kernel(const ushort_t* __restrict__ qkv,
                                                      ushort_t* __restrict__ out) {
    __shared__ __attribute__((aligned(16))) ushort_t Ks[2][64 * 64];
    __shared__ __attribute__((aligned(16))) ushort_t Vt[2][64 * 64];
    __shared__ __attribute__((aligned(16))) ushort_t Pl[4][16 * 64];
    const int tid = threadIdx.x;
    const int wave = tid >> 6, lane = tid & 63;
    const int l15 = lane & 15, l4 = lane >> 4;
    const int bq = ((int)gridDim.x - 1) - (int)blockIdx.x;   // heavy blocks first
    const int bh = blockIdx.y;
    const int b = bh >> 4, h = bh & 15;
    const int qbase = bq * 64 + wave * 16;
    const size_t rowbase = (size_t)b * SEQ;

    AState S;
    attn_init(S, qkv, rowbase, qbase, h, l15, l4);

    // staging lane geometry
    const int krow = lane >> 3;                 // 0..7
    const int kch = (lane & 7) ^ krow;          // pre-swizzled source chunk
    const int sv_key = tid & 63, sv_d0 = (tid >> 6) * 16;
    const ushort_t* gk = qkv + (rowbase + wave * 16 + krow) * 3072 + 1024 + h * 64 + kch * 8;
    const ushort_t* gv = qkv + (rowbase + sv_key) * 3072 + 2048 + h * 64 + sv_d0;

    // ---- prologue: stage tile 0 into buffer 0 ----
    glds16(gk, &Ks[0][(wave * 16) * 64]);
    glds16(gk + (size_t)8 * 3072, &Ks[0][(wave * 16 + 8) * 64]);
    {
        bf16x8 v0 = *(const bf16x8*)gv;
        bf16x8 v1 = *(const bf16x8*)(gv + 8);
        scatterV(Vt[0], v0, v1, sv_key, sv_d0);
    }
    __syncthreads();

    const int nt = bq + 1;
    for (int t = 0; t < nt; ++t) {
        const int db = t & 1;
        const bool more = (t + 1 < nt);
        bf16x8 nv0, nv1;
        if (more) {
            const size_t koff = (size_t)(t + 1) * 64 * 3072;
            glds16(gk + koff, &Ks[db ^ 1][(wave * 16) * 64]);
            glds16(gk + koff + (size_t)8 * 3072, &Ks[db ^ 1][(wave * 16 + 8) * 64]);
            nv0 = *(const bf16x8*)(gv + koff);
            nv1 = *(const bf16x8*)(gv + koff + 8);
        }
        attn_tile(S, Ks[db], Vt[db], Pl[wave], l15, l4, qbase + l15 - t * 64);
        if (more)
            scatterV(Vt[db ^ 1], nv0, nv1, sv_key, sv_d0);
        __syncthreads();   // next tile fully staged; old buffers free
    }

    attn_store(S, out, rowbase, qbase, h, l15, l4);
}

// ---------------- launcher ----------------
extern "C" void kernel_launch(void* const* d_in, const int* in_sizes, int n_in,
                              void* d_out, int out_size, void* d_ws, size_t ws_size,
                              hipStream_t stream) {
    const float* x     = (const float*)d_in[0];
    // d_in[1] = mask (causal, implemented analytically)
    const float* W_qkv = (const float*)d_in[2];
    const float* b_qkv = (const float*)d_in[3];
    const float* W_out = (const float*)d_in[4];
    const float* b_out = (const float*)d_in[5];
    float* out = (float*)d_out;

    char* ws = (char*)d_ws;
    ushort_t* xb    = (ushort_t*)(ws);                      // 16,777,216 B
    ushort_t* WqkvT = (ushort_t*)(ws + 16777216);           //  6,291,456 B
    ushort_t* WoutT = (ushort_t*)(ws + 23068672);           //  2,097,152 B
    ushort_t* qkv   = (ushort_t*)(ws + 25165824);           // 50,331,648 B
    ushort_t* attn  = (ushort_t*)(ws + 75497472);           // 16,777,216 B

    const int nx = BATCH * SEQ * DM;                        // 8,388,608
    cast_f32_bf16<<<nx / (256 * 4), 256, 0, stream>>>(x, xb, nx);
    transpose_cast<<<dim3(3 * DM / 32, DM / 32), dim3(32, 8), 0, stream>>>(W_qkv, WqkvT, DM, 3 * DM);
    transpose_cast<<<dim3(DM / 32, DM / 32), dim3(32, 8), 0, stream>>>(W_out, WoutT, DM, DM);

    // QKV projection: [8192,1024] @ [1024,3072] -> bf16 qkv
    gemm_abt<false><<<dim3(3 * DM / 128, BATCH * SEQ / 128), 256, 0, stream>>>(
        xb, WqkvT, b_qkv, qkv, BATCH * SEQ, 3 * DM, DM);

    // attention
    attn_kernel<<<dim3(SEQ / 64, BATCH * NH), 256, 0, stream>>>(qkv, attn);

    // output projection: [8192,1024] @ [1024,1024] -> f32 out
    gemm_abt<true><<<dim3(DM / 128, BATCH * SEQ / 128), 256, 0, stream>>>(
        attn, WoutT, b_out, out, BATCH * SEQ, DM, DM);
}

// Round 5
// 289.764 us; speedup vs baseline: 1.8360x; 1.2331x over previous
//
#include <hip/hip_runtime.h>

// ---------------- problem constants ----------------
#define BATCH 4
#define SEQ 2048
#define DM 1024
#define NH 16
#define SCALE 0.125f   // 64^-0.5

typedef unsigned short ushort_t;
typedef short bf16x8 __attribute__((ext_vector_type(8)));
typedef float f32x4 __attribute__((ext_vector_type(4)));

__device__ __forceinline__ ushort_t f2bf(float f) {
    unsigned u = __float_as_uint(f);
    unsigned r = (u + 0x7FFFu + ((u >> 16) & 1u)) >> 16;
    return (ushort_t)r;
}

__device__ __forceinline__ unsigned cvtpk_bf16(float lo, float hi) {
    unsigned r;
    asm("v_cvt_pk_bf16_f32 %0, %1, %2" : "=v"(r) : "v"(lo), "v"(hi));
    return r;
}

__device__ __forceinline__ void glds16(const ushort_t* g, ushort_t* l) {
    __builtin_amdgcn_global_load_lds(
        (const __attribute__((address_space(1))) unsigned*)g,
        (__attribute__((address_space(3))) unsigned*)l, 16, 0, 0);
}

// ---------------- cast x: f32 -> bf16, 4 elems/thread ----------------
__global__ void cast_f32_bf16(const float* __restrict__ in, ushort_t* __restrict__ out, int n) {
    int i = (blockIdx.x * blockDim.x + threadIdx.x) * 4;
    if (i < n) {
        float4 v = *(const float4*)(in + i);
        ushort4 o;
        o.x = f2bf(v.x); o.y = f2bf(v.y); o.z = f2bf(v.z); o.w = f2bf(v.w);
        *(ushort4*)(out + i) = o;
    }
}

// ---------------- transpose+cast: in[K][N] f32 -> out[N][K] bf16 ----------------
__global__ void transpose_cast(const float* __restrict__ in, ushort_t* __restrict__ out,
                               int K, int N) {
    __shared__ float tile[32][33];
    int n0 = blockIdx.x * 32, k0 = blockIdx.y * 32;
    int x = threadIdx.x, y = threadIdx.y;   // blockDim = (32, 8)
#pragma unroll
    for (int j = 0; j < 32; j += 8)
        tile[y + j][x] = in[(size_t)(k0 + y + j) * N + n0 + x];
    __syncthreads();
#pragma unroll
    for (int j = 0; j < 32; j += 8)
        out[(size_t)(n0 + y + j) * K + k0 + x] = f2bf(tile[x][y + j]);
}

// ---------------- GEMM: C[M][N] = A[M][K] @ Bt[N][K]^T + bias[N] ----------------
// 128x128 tile, 4 waves (2x2), BK=64, global_load_lds width=16 into linear
// [128][64] LDS with XOR chunk swizzle. 32 MFMA per barrier pair. (unchanged)
template <bool OUT_F32>
__global__ __launch_bounds__(256) void gemm_abt(
    const ushort_t* __restrict__ A, const ushort_t* __restrict__ Bt,
    const float* __restrict__ bias, void* __restrict__ Cout,
    int M, int N, int K) {
    __shared__ __attribute__((aligned(16))) ushort_t As[128 * 64];
    __shared__ __attribute__((aligned(16))) ushort_t Bs[128 * 64];
    const int tid = threadIdx.x;
    const int lane = tid & 63, wave = tid >> 6;
    const int l15 = lane & 15, l4 = lane >> 4;
    const int m0 = blockIdx.y * 128, n0 = blockIdx.x * 128;
    const int wr = (wave >> 1) * 64, wc = (wave & 1) * 64;
    const int r8 = lane >> 3;
    const int kch = (lane & 7) ^ r8;
    const ushort_t* gA = A + (size_t)(m0 + wave * 32 + r8) * K + kch * 8;
    const ushort_t* gB = Bt + (size_t)(n0 + wave * 32 + r8) * K + kch * 8;
    const int r7 = l15 & 7;

    f32x4 acc[4][4];
#pragma unroll
    for (int i = 0; i < 4; ++i)
#pragma unroll
        for (int j = 0; j < 4; ++j) acc[i][j] = (f32x4){0.f, 0.f, 0.f, 0.f};

    for (int k0 = 0; k0 < K; k0 += 64) {
#pragma unroll
        for (int c = 0; c < 4; ++c) {
            glds16(gA + k0 + (size_t)(c * 8) * K, &As[(wave * 32 + c * 8) * 64]);
            glds16(gB + k0 + (size_t)(c * 8) * K, &Bs[(wave * 32 + c * 8) * 64]);
        }
        __syncthreads();
#pragma unroll
        for (int kh = 0; kh < 2; ++kh) {
            const int ch = ((kh * 4 + l4) ^ r7) * 8;
            bf16x8 a[4], b[4];
#pragma unroll
            for (int i = 0; i < 4; ++i) {
                a[i] = *(const bf16x8*)&As[(wr + i * 16 + l15) * 64 + ch];
                b[i] = *(const bf16x8*)&Bs[(wc + i * 16 + l15) * 64 + ch];
            }
#pragma unroll
            for (int mi = 0; mi < 4; ++mi)
#pragma unroll
                for (int ni = 0; ni < 4; ++ni)
                    acc[mi][ni] = __builtin_amdgcn_mfma_f32_16x16x32_bf16(
                        a[mi], b[ni], acc[mi][ni], 0, 0, 0);
        }
        __syncthreads();
    }

#pragma unroll
    for (int mi = 0; mi < 4; ++mi)
#pragma unroll
        for (int ni = 0; ni < 4; ++ni)
#pragma unroll
            for (int r = 0; r < 4; ++r) {
                int row = m0 + wr + mi * 16 + l4 * 4 + r;
                int col = n0 + wc + ni * 16 + l15;
                float v = acc[mi][ni][r] + bias[col];
                if (OUT_F32)
                    ((float*)Cout)[(size_t)row * N + col] = v;
                else
                    ((ushort_t*)Cout)[(size_t)row * N + col] = f2bf(v);
            }
}

// ---------------- flash attention ----------------
// Block (bh,pair) processes q-blocks 31-pair then pair SEQUENTIALLY (one
// AState live -> no spill; round-3 lesson). Every block = 33 tile-units,
// 1024 blocks = exactly 4/CU all-resident -> flat ~50% occupancy, no tail.
// K/V double-buffered (K via global_load_lds, V reg-staged T14 split).
// Softmax: SCALE folded into exp2 arg, cvt_pk P->bf16, defer-max (THR raw 64).
struct AState {
    bf16x8 q0, q1;
    f32x4 o[4];
    float m, l;
};

__device__ __forceinline__ void scatterV(ushort_t* V, bf16x8 v0, bf16x8 v1, int key, int d0) {
#pragma unroll
    for (int j = 0; j < 8; ++j) {
        int d = d0 + j;
        V[d * 64 + (key ^ ((d & 7) << 3))] = (ushort_t)v0[j];
        int d2 = d0 + 8 + j;
        V[d2 * 64 + (key ^ ((d2 & 7) << 3))] = (ushort_t)v1[j];
    }
}

#define EXPC 0.18033688011112042f   // SCALE * log2(e)

__device__ __forceinline__ void attn_tile(AState& S, const ushort_t* __restrict__ Ks,
                                          const ushort_t* __restrict__ Vt,
                                          ushort_t* __restrict__ Plw,
                                          int l15, int l4, int rel) {
    // QK^T (swapped): S^T[key][q], key=(l4*4+r)+16*kt, q=l15. Raw scores.
    float p[16];
    float pmax = -INFINITY;
    __builtin_amdgcn_s_setprio(1);
#pragma unroll
    for (int kt = 0; kt < 4; ++kt) {
        const int row = kt * 16 + l15, r7 = row & 7;
        bf16x8 ak0 = *(const bf16x8*)&Ks[row * 64 + ((l4 ^ r7) * 8)];
        bf16x8 ak1 = *(const bf16x8*)&Ks[row * 64 + (((4 + l4) ^ r7) * 8)];
        f32x4 z = {0.f, 0.f, 0.f, 0.f};
        z = __builtin_amdgcn_mfma_f32_16x16x32_bf16(ak0, S.q0, z, 0, 0, 0);
        z = __builtin_amdgcn_mfma_f32_16x16x32_bf16(ak1, S.q1, z, 0, 0, 0);
#pragma unroll
        for (int r = 0; r < 4; ++r) {
            float v = (kt * 16 + l4 * 4 + r > rel) ? -INFINITY : z[r];
            p[kt * 4 + r] = v;
            pmax = fmaxf(pmax, v);
        }
    }
    __builtin_amdgcn_s_setprio(0);
    pmax = fmaxf(pmax, __shfl_xor(pmax, 16));
    pmax = fmaxf(pmax, __shfl_xor(pmax, 32));

    // defer-max: skip rescale when growth small (raw THR 64 == scaled 8)
    const bool defer = __all(pmax - S.m <= 64.f);
    const float mref = defer ? S.m : fmaxf(S.m, pmax);
    const float mC = mref * EXPC;
    float rsum = 0.f;
#pragma unroll
    for (int i = 0; i < 16; ++i) {
        p[i] = __builtin_exp2f(fmaf(p[i], EXPC, -mC));
        rsum += p[i];
    }
    rsum += __shfl_xor(rsum, 16);
    rsum += __shfl_xor(rsum, 32);
    if (defer) {
        S.l += rsum;
    } else {
        const float scl = __builtin_exp2f((S.m - mref) * EXPC);   // 0 on first tile
        S.l = S.l * scl + rsum;
        S.m = mref;
        const float sc0 = __shfl(scl, l4 * 4 + 0);
        const float sc1 = __shfl(scl, l4 * 4 + 1);
        const float sc2 = __shfl(scl, l4 * 4 + 2);
        const float sc3 = __shfl(scl, l4 * 4 + 3);
#pragma unroll
        for (int dt = 0; dt < 4; ++dt) {
            S.o[dt][0] *= sc0; S.o[dt][1] *= sc1; S.o[dt][2] *= sc2; S.o[dt][3] *= sc3;
        }
    }

    // P -> LDS (swizzled) via packed cvt, row q=l15
    const int pr7 = l15 & 7;
#pragma unroll
    for (int kt = 0; kt < 4; ++kt) {
        uint2 w;
        w.x = cvtpk_bf16(p[kt * 4 + 0], p[kt * 4 + 1]);
        w.y = cvtpk_bf16(p[kt * 4 + 2], p[kt * 4 + 3]);
        *(uint2*)&Plw[l15 * 64 + ((kt * 16 + l4 * 4) ^ (pr7 << 3))] = w;
    }

    // PV
    bf16x8 pa0 = *(const bf16x8*)&Plw[l15 * 64 + ((l4 ^ pr7) * 8)];
    bf16x8 pa1 = *(const bf16x8*)&Plw[l15 * 64 + (((4 + l4) ^ pr7) * 8)];
    __builtin_amdgcn_s_setprio(1);
#pragma unroll
    for (int dt = 0; dt < 4; ++dt) {
        const int d = dt * 16 + l15, r7 = d & 7;
        bf16x8 bv0 = *(const bf16x8*)&Vt[d * 64 + ((l4 ^ r7) * 8)];
        bf16x8 bv1 = *(const bf16x8*)&Vt[d * 64 + (((4 + l4) ^ r7) * 8)];
        S.o[dt] = __builtin_amdgcn_mfma_f32_16x16x32_bf16(pa0, bv0, S.o[dt], 0, 0, 0);
        S.o[dt] = __builtin_amdgcn_mfma_f32_16x16x32_bf16(pa1, bv1, S.o[dt], 0, 0, 0);
    }
    __builtin_amdgcn_s_setprio(0);
}

__device__ __forceinline__ void process_qblock(
    int bq, const ushort_t* __restrict__ qkv, ushort_t* __restrict__ out,
    size_t rowbase, int h, int wave, int l15, int l4,
    const ushort_t* gk, const ushort_t* gv, int sv_key, int sv_d0,
    ushort_t* Ks0, ushort_t* Ks1, ushort_t* Vt0, ushort_t* Vt1, ushort_t* Plw) {
    const int qbase = bq * 64 + wave * 16;

    AState S;
    {
        const ushort_t* qp = qkv + (rowbase + qbase + l15) * 3072 + h * 64 + l4 * 8;
        S.q0 = *(const bf16x8*)qp;
        S.q1 = *(const bf16x8*)(qp + 32);
    }
#pragma unroll
    for (int i = 0; i < 4; ++i) S.o[i] = (f32x4){0.f, 0.f, 0.f, 0.f};
    S.m = -INFINITY;
    S.l = 0.f;

    // prologue: stage tile 0 into buffer 0
    glds16(gk, &Ks0[(wave * 16) * 64]);
    glds16(gk + (size_t)8 * 3072, &Ks0[(wave * 16 + 8) * 64]);
    {
        bf16x8 v0 = *(const bf16x8*)gv;
        bf16x8 v1 = *(const bf16x8*)(gv + 8);
        scatterV(Vt0, v0, v1, sv_key, sv_d0);
    }
    __syncthreads();

    const int nt = bq + 1;
    for (int t = 0; t < nt; ++t) {
        ushort_t* Kc = (t & 1) ? Ks1 : Ks0;
        ushort_t* Vc = (t & 1) ? Vt1 : Vt0;
        ushort_t* Kn = (t & 1) ? Ks0 : Ks1;
        ushort_t* Vn = (t & 1) ? Vt0 : Vt1;
        const bool more = (t + 1 < nt);
        bf16x8 nv0, nv1;
        if (more) {
            const size_t koff = (size_t)(t + 1) * 64 * 3072;
            glds16(gk + koff, &Kn[(wave * 16) * 64]);
            glds16(gk + koff + (size_t)8 * 3072, &Kn[(wave * 16 + 8) * 64]);
            nv0 = *(const bf16x8*)(gv + koff);
            nv1 = *(const bf16x8*)(gv + koff + 8);
        }
        attn_tile(S, Kc, Vc, Plw, l15, l4, qbase + l15 - t * 64);
        if (more)
            scatterV(Vn, nv0, nv1, sv_key, sv_d0);
        __syncthreads();   // next tile fully staged; old buffers free
    }

    // epilogue: normalize and store
    const float li0 = __shfl(S.l, l4 * 4 + 0);
    const float li1 = __shfl(S.l, l4 * 4 + 1);
    const float li2 = __shfl(S.l, l4 * 4 + 2);
    const float li3 = __shfl(S.l, l4 * 4 + 3);
#pragma unroll
    for (int r = 0; r < 4; ++r) {
        const int qr = qbase + l4 * 4 + r;
        const float li = (r == 0) ? li0 : (r == 1) ? li1 : (r == 2) ? li2 : li3;
        ushort_t* op = out + (rowbase + qr) * DM + h * 64 + l15;
#pragma unroll
        for (int dt = 0; dt < 4; ++dt)
            op[dt * 16] = f2bf(S.o[dt][r] / li);
    }
}

__global__ __launch_bounds__(256, 4) void attn_kernel(const ushort_t* __restrict__ qkv,
                                                      ushort_t* __restrict__ out) {
    __shared__ __attribute__((aligned(16))) ushort_t Ks[2][64 * 64];
    __shared__ __attribute__((aligned(16))) ushort_t Vt[2][64 * 64];
    __shared__ __attribute__((aligned(16))) ushort_t Pl[4][16 * 64];
    const int tid = threadIdx.x;
    const int wave = tid >> 6, lane = tid & 63;
    const int l15 = lane & 15, l4 = lane >> 4;
    const int bh = blockIdx.x;                  // 0..63
    const int b = bh >> 4, h = bh & 15;
    const int pair = blockIdx.y;                // 0..15
    const size_t rowbase = (size_t)b * SEQ;

    // staging lane geometry (q-block independent)
    const int krow = lane >> 3;                 // 0..7
    const int kch = (lane & 7) ^ krow;          // pre-swizzled source chunk
    const int sv_key = tid & 63, sv_d0 = (tid >> 6) * 16;
    const ushort_t* gk = qkv + (rowbase + wave * 16 + krow) * 3072 + 1024 + h * 64 + kch * 8;
    const ushort_t* gv = qkv + (rowbase + sv_key) * 3072 + 2048 + h * 64 + sv_d0;

    process_qblock(31 - pair, qkv, out, rowbase, h, wave, l15, l4,
                   gk, gv, sv_key, sv_d0, Ks[0], Ks[1], Vt[0], Vt[1], Pl[wave]);
    process_qblock(pair, qkv, out, rowbase, h, wave, l15, l4,
                   gk, gv, sv_key, sv_d0, Ks[0], Ks[1], Vt[0], Vt[1], Pl[wave]);
}

// ---------------- launcher ----------------
extern "C" void kernel_launch(void* const* d_in, const int* in_sizes, int n_in,
                              void* d_out, int out_size, void* d_ws, size_t ws_size,
                              hipStream_t stream) {
    const float* x     = (const float*)d_in[0];
    // d_in[1] = mask (causal, implemented analytically)
    const float* W_qkv = (const float*)d_in[2];
    const float* b_qkv = (const float*)d_in[3];
    const float* W_out = (const float*)d_in[4];
    const float* b_out = (const float*)d_in[5];
    float* out = (float*)d_out;

    char* ws = (char*)d_ws;
    ushort_t* xb    = (ushort_t*)(ws);                      // 16,777,216 B
    ushort_t* WqkvT = (ushort_t*)(ws + 16777216);           //  6,291,456 B
    ushort_t* WoutT = (ushort_t*)(ws + 23068672);           //  2,097,152 B
    ushort_t* qkv   = (ushort_t*)(ws + 25165824);           // 50,331,648 B
    ushort_t* attn  = (ushort_t*)(ws + 75497472);           // 16,777,216 B

    const int nx = BATCH * SEQ * DM;                        // 8,388,608
    cast_f32_bf16<<<nx / (256 * 4), 256, 0, stream>>>(x, xb, nx);
    transpose_cast<<<dim3(3 * DM / 32, DM / 32), dim3(32, 8), 0, stream>>>(W_qkv, WqkvT, DM, 3 * DM);
    transpose_cast<<<dim3(DM / 32, DM / 32), dim3(32, 8), 0, stream>>>(W_out, WoutT, DM, DM);

    // QKV projection: [8192,1024] @ [1024,3072] -> bf16 qkv
    gemm_abt<false><<<dim3(3 * DM / 128, BATCH * SEQ / 128), 256, 0, stream>>>(
        xb, WqkvT, b_qkv, qkv, BATCH * SEQ, 3 * DM, DM);

    // attention: balanced sequential-pair blocks, 1024 = 4/CU all resident
    attn_kernel<<<dim3(BATCH * NH, SEQ / 128), 256, 0, stream>>>(qkv, attn);

    // output projection: [8192,1024] @ [1024,1024] -> f32 out
    gemm_abt<true><<<dim3(DM / 128, BATCH * SEQ / 128), 256, 0, stream>>>(
        attn, WoutT, b_out, out, BATCH * SEQ, DM, DM);
}

// Round 6
// 286.833 us; speedup vs baseline: 1.8548x; 1.0102x over previous
//
#include <hip/hip_runtime.h>

// ---------------- problem constants ----------------
#define BATCH 4
#define SEQ 2048
#define DM 1024
#define NH 16
#define SCALE 0.125f   // 64^-0.5

typedef unsigned short ushort_t;
typedef short bf16x8 __attribute__((ext_vector_type(8)));
typedef float f32x4 __attribute__((ext_vector_type(4)));

__device__ __forceinline__ ushort_t f2bf(float f) {
    unsigned u = __float_as_uint(f);
    unsigned r = (u + 0x7FFFu + ((u >> 16) & 1u)) >> 16;
    return (ushort_t)r;
}

__device__ __forceinline__ unsigned cvtpk_bf16(float lo, float hi) {
    unsigned r;
    asm("v_cvt_pk_bf16_f32 %0, %1, %2" : "=v"(r) : "v"(lo), "v"(hi));
    return r;
}

__device__ __forceinline__ void glds16(const ushort_t* g, ushort_t* l) {
    __builtin_amdgcn_global_load_lds(
        (const __attribute__((address_space(1))) unsigned*)g,
        (__attribute__((address_space(3))) unsigned*)l, 16, 0, 0);
}

// ---------------- cast x: f32 -> bf16, 4 elems/thread ----------------
__global__ void cast_f32_bf16(const float* __restrict__ in, ushort_t* __restrict__ out, int n) {
    int i = (blockIdx.x * blockDim.x + threadIdx.x) * 4;
    if (i < n) {
        float4 v = *(const float4*)(in + i);
        ushort4 o;
        o.x = f2bf(v.x); o.y = f2bf(v.y); o.z = f2bf(v.z); o.w = f2bf(v.w);
        *(ushort4*)(out + i) = o;
    }
}

// ---------------- transpose+cast: in[K][N] f32 -> out[N][K] bf16 ----------------
__global__ void transpose_cast(const float* __restrict__ in, ushort_t* __restrict__ out,
                               int K, int N) {
    __shared__ float tile[32][33];
    int n0 = blockIdx.x * 32, k0 = blockIdx.y * 32;
    int x = threadIdx.x, y = threadIdx.y;   // blockDim = (32, 8)
#pragma unroll
    for (int j = 0; j < 32; j += 8)
        tile[y + j][x] = in[(size_t)(k0 + y + j) * N + n0 + x];
    __syncthreads();
#pragma unroll
    for (int j = 0; j < 32; j += 8)
        out[(size_t)(n0 + y + j) * K + k0 + x] = f2bf(tile[x][y + j]);
}

// ---------------- shared GEMM core macro-parts ----------------
// 128x128 tile, 4 waves (2x2), BK=64, global_load_lds width=16 into linear
// [128][64] LDS with XOR chunk swizzle. 32 MFMA per barrier pair.

// QKV GEMM: writes Q,K to qk[row][0..2047] (stride 2048) and V TRANSPOSED to
// vt[(b*1024 + h*64+hd)][s] (stride 2048). n0>=2048 <=> V block (uniform).
__global__ __launch_bounds__(256) void gemm_qkv(
    const ushort_t* __restrict__ A, const ushort_t* __restrict__ Bt,
    const float* __restrict__ bias, ushort_t* __restrict__ qk,
    ushort_t* __restrict__ vt, int M, int N, int K) {
    __shared__ __attribute__((aligned(16))) ushort_t As[128 * 64];
    __shared__ __attribute__((aligned(16))) ushort_t Bs[128 * 64];
    const int tid = threadIdx.x;
    const int lane = tid & 63, wave = tid >> 6;
    const int l15 = lane & 15, l4 = lane >> 4;
    const int m0 = blockIdx.y * 128, n0 = blockIdx.x * 128;
    const int wr = (wave >> 1) * 64, wc = (wave & 1) * 64;
    const int r8 = lane >> 3;
    const int kch = (lane & 7) ^ r8;
    const ushort_t* gA = A + (size_t)(m0 + wave * 32 + r8) * K + kch * 8;
    const ushort_t* gB = Bt + (size_t)(n0 + wave * 32 + r8) * K + kch * 8;
    const int r7 = l15 & 7;

    f32x4 acc[4][4];
#pragma unroll
    for (int i = 0; i < 4; ++i)
#pragma unroll
        for (int j = 0; j < 4; ++j) acc[i][j] = (f32x4){0.f, 0.f, 0.f, 0.f};

    for (int k0 = 0; k0 < K; k0 += 64) {
#pragma unroll
        for (int c = 0; c < 4; ++c) {
            glds16(gA + k0 + (size_t)(c * 8) * K, &As[(wave * 32 + c * 8) * 64]);
            glds16(gB + k0 + (size_t)(c * 8) * K, &Bs[(wave * 32 + c * 8) * 64]);
        }
        __syncthreads();
#pragma unroll
        for (int kh = 0; kh < 2; ++kh) {
            const int ch = ((kh * 4 + l4) ^ r7) * 8;
            bf16x8 a[4], b[4];
#pragma unroll
            for (int i = 0; i < 4; ++i) {
                a[i] = *(const bf16x8*)&As[(wr + i * 16 + l15) * 64 + ch];
                b[i] = *(const bf16x8*)&Bs[(wc + i * 16 + l15) * 64 + ch];
            }
#pragma unroll
            for (int mi = 0; mi < 4; ++mi)
#pragma unroll
                for (int ni = 0; ni < 4; ++ni)
                    acc[mi][ni] = __builtin_amdgcn_mfma_f32_16x16x32_bf16(
                        a[mi], b[ni], acc[mi][ni], 0, 0, 0);
        }
        __syncthreads();
    }

    if (n0 < 2048) {
        // Q/K block: normal [row][col] store, stride 2048
#pragma unroll
        for (int mi = 0; mi < 4; ++mi)
#pragma unroll
            for (int ni = 0; ni < 4; ++ni) {
                const int col = n0 + wc + ni * 16 + l15;
                const float bv = bias[col];
#pragma unroll
                for (int r = 0; r < 4; ++r) {
                    const int row = m0 + wr + mi * 16 + l4 * 4 + r;
                    qk[(size_t)row * 2048 + col] = f2bf(acc[mi][ni][r] + bv);
                }
            }
    } else {
        // V block: transposed store vt[b*1024 + hdg][s], 4 consecutive s packed
#pragma unroll
        for (int mi = 0; mi < 4; ++mi)
#pragma unroll
            for (int ni = 0; ni < 4; ++ni) {
                const int hdg = n0 + wc + ni * 16 + l15 - 2048;
                const float bv = bias[2048 + hdg];
                const int row0 = m0 + wr + mi * 16 + l4 * 4;
                const int bb = row0 >> 11, s0 = row0 & 2047;
                ushort4 pk;
                pk.x = f2bf(acc[mi][ni][0] + bv);
                pk.y = f2bf(acc[mi][ni][1] + bv);
                pk.z = f2bf(acc[mi][ni][2] + bv);
                pk.w = f2bf(acc[mi][ni][3] + bv);
                *(ushort4*)&vt[((size_t)bb * 1024 + hdg) * 2048 + s0] = pk;
            }
    }
}

// out-projection GEMM (unchanged structure), f32 output
__global__ __launch_bounds__(256) void gemm_abt(
    const ushort_t* __restrict__ A, const ushort_t* __restrict__ Bt,
    const float* __restrict__ bias, float* __restrict__ Cout,
    int M, int N, int K) {
    __shared__ __attribute__((aligned(16))) ushort_t As[128 * 64];
    __shared__ __attribute__((aligned(16))) ushort_t Bs[128 * 64];
    const int tid = threadIdx.x;
    const int lane = tid & 63, wave = tid >> 6;
    const int l15 = lane & 15, l4 = lane >> 4;
    const int m0 = blockIdx.y * 128, n0 = blockIdx.x * 128;
    const int wr = (wave >> 1) * 64, wc = (wave & 1) * 64;
    const int r8 = lane >> 3;
    const int kch = (lane & 7) ^ r8;
    const ushort_t* gA = A + (size_t)(m0 + wave * 32 + r8) * K + kch * 8;
    const ushort_t* gB = Bt + (size_t)(n0 + wave * 32 + r8) * K + kch * 8;
    const int r7 = l15 & 7;

    f32x4 acc[4][4];
#pragma unroll
    for (int i = 0; i < 4; ++i)
#pragma unroll
        for (int j = 0; j < 4; ++j) acc[i][j] = (f32x4){0.f, 0.f, 0.f, 0.f};

    for (int k0 = 0; k0 < K; k0 += 64) {
#pragma unroll
        for (int c = 0; c < 4; ++c) {
            glds16(gA + k0 + (size_t)(c * 8) * K, &As[(wave * 32 + c * 8) * 64]);
            glds16(gB + k0 + (size_t)(c * 8) * K, &Bs[(wave * 32 + c * 8) * 64]);
        }
        __syncthreads();
#pragma unroll
        for (int kh = 0; kh < 2; ++kh) {
            const int ch = ((kh * 4 + l4) ^ r7) * 8;
            bf16x8 a[4], b[4];
#pragma unroll
            for (int i = 0; i < 4; ++i) {
                a[i] = *(const bf16x8*)&As[(wr + i * 16 + l15) * 64 + ch];
                b[i] = *(const bf16x8*)&Bs[(wc + i * 16 + l15) * 64 + ch];
            }
#pragma unroll
            for (int mi = 0; mi < 4; ++mi)
#pragma unroll
                for (int ni = 0; ni < 4; ++ni)
                    acc[mi][ni] = __builtin_amdgcn_mfma_f32_16x16x32_bf16(
                        a[mi], b[ni], acc[mi][ni], 0, 0, 0);
        }
        __syncthreads();
    }

#pragma unroll
    for (int mi = 0; mi < 4; ++mi)
#pragma unroll
        for (int ni = 0; ni < 4; ++ni)
#pragma unroll
            for (int r = 0; r < 4; ++r) {
                const int row = m0 + wr + mi * 16 + l4 * 4 + r;
                const int col = n0 + wc + ni * 16 + l15;
                Cout[(size_t)row * N + col] = acc[mi][ni][r] + bias[col];
            }
}

// ---------------- flash attention ----------------
// qk: [B*S][2048] bf16 (Q +0, K +1024; head at h*64)
// vt: [(b*1024 + h*64+hd)][2048 s] bf16 — V pre-transposed by gemm_qkv.
// Block (bh,pair): q-blocks 31-pair then pair sequentially (balanced, no
// spill). K and V both staged via global_load_lds with pre-swizzled source.
// Mask only on diagonal tile (template). Softmax: exp2 folded-scale, cvt_pk,
// defer-max.
struct AState {
    bf16x8 q0, q1;
    f32x4 o[4];
    float m, l;
};

#define EXPC 0.18033688011112042f   // SCALE * log2(e)

template <bool MASK>
__device__ __forceinline__ void attn_tile(AState& S, const ushort_t* __restrict__ Ks,
                                          const ushort_t* __restrict__ Vt,
                                          ushort_t* __restrict__ Plw,
                                          int l15, int l4, int rel) {
    // QK^T (swapped): S^T[key][q], key=(l4*4+r)+16*kt, q=l15. Raw scores.
    float p[16];
    float pmax = -INFINITY;
    __builtin_amdgcn_s_setprio(1);
#pragma unroll
    for (int kt = 0; kt < 4; ++kt) {
        const int row = kt * 16 + l15, r7 = row & 7;
        bf16x8 ak0 = *(const bf16x8*)&Ks[row * 64 + ((l4 ^ r7) * 8)];
        bf16x8 ak1 = *(const bf16x8*)&Ks[row * 64 + (((4 + l4) ^ r7) * 8)];
        f32x4 z = {0.f, 0.f, 0.f, 0.f};
        z = __builtin_amdgcn_mfma_f32_16x16x32_bf16(ak0, S.q0, z, 0, 0, 0);
        z = __builtin_amdgcn_mfma_f32_16x16x32_bf16(ak1, S.q1, z, 0, 0, 0);
#pragma unroll
        for (int r = 0; r < 4; ++r) {
            float v = z[r];
            if (MASK) v = (kt * 16 + l4 * 4 + r > rel) ? -INFINITY : v;
            p[kt * 4 + r] = v;
            pmax = fmaxf(pmax, v);
        }
    }
    __builtin_amdgcn_s_setprio(0);
    pmax = fmaxf(pmax, __shfl_xor(pmax, 16));
    pmax = fmaxf(pmax, __shfl_xor(pmax, 32));

    // defer-max: skip rescale when growth small (raw THR 64 == scaled 8)
    const bool defer = __all(pmax - S.m <= 64.f);
    const float mref = defer ? S.m : fmaxf(S.m, pmax);
    const float mC = mref * EXPC;
    float rsum = 0.f;
#pragma unroll
    for (int i = 0; i < 16; ++i) {
        p[i] = __builtin_exp2f(fmaf(p[i], EXPC, -mC));
        rsum += p[i];
    }
    rsum += __shfl_xor(rsum, 16);
    rsum += __shfl_xor(rsum, 32);
    if (defer) {
        S.l += rsum;
    } else {
        const float scl = __builtin_exp2f((S.m - mref) * EXPC);   // 0 on first tile
        S.l = S.l * scl + rsum;
        S.m = mref;
        const float sc0 = __shfl(scl, l4 * 4 + 0);
        const float sc1 = __shfl(scl, l4 * 4 + 1);
        const float sc2 = __shfl(scl, l4 * 4 + 2);
        const float sc3 = __shfl(scl, l4 * 4 + 3);
#pragma unroll
        for (int dt = 0; dt < 4; ++dt) {
            S.o[dt][0] *= sc0; S.o[dt][1] *= sc1; S.o[dt][2] *= sc2; S.o[dt][3] *= sc3;
        }
    }

    // P -> LDS (swizzled) via packed cvt, row q=l15
    const int pr7 = l15 & 7;
#pragma unroll
    for (int kt = 0; kt < 4; ++kt) {
        uint2 w;
        w.x = cvtpk_bf16(p[kt * 4 + 0], p[kt * 4 + 1]);
        w.y = cvtpk_bf16(p[kt * 4 + 2], p[kt * 4 + 3]);
        *(uint2*)&Plw[l15 * 64 + ((kt * 16 + l4 * 4) ^ (pr7 << 3))] = w;
    }

    // PV
    bf16x8 pa0 = *(const bf16x8*)&Plw[l15 * 64 + ((l4 ^ pr7) * 8)];
    bf16x8 pa1 = *(const bf16x8*)&Plw[l15 * 64 + (((4 + l4) ^ pr7) * 8)];
    __builtin_amdgcn_s_setprio(1);
#pragma unroll
    for (int dt = 0; dt < 4; ++dt) {
        const int d = dt * 16 + l15, r7 = d & 7;
        bf16x8 bv0 = *(const bf16x8*)&Vt[d * 64 + ((l4 ^ r7) * 8)];
        bf16x8 bv1 = *(const bf16x8*)&Vt[d * 64 + (((4 + l4) ^ r7) * 8)];
        S.o[dt] = __builtin_amdgcn_mfma_f32_16x16x32_bf16(pa0, bv0, S.o[dt], 0, 0, 0);
        S.o[dt] = __builtin_amdgcn_mfma_f32_16x16x32_bf16(pa1, bv1, S.o[dt], 0, 0, 0);
    }
    __builtin_amdgcn_s_setprio(0);
}

__device__ __forceinline__ void process_qblock(
    int bq, const ushort_t* __restrict__ qk, ushort_t* __restrict__ out,
    size_t rowbase, int h, int wave, int l15, int l4,
    const ushort_t* gk, const ushort_t* gvt,
    ushort_t* Ks0, ushort_t* Ks1, ushort_t* Vt0, ushort_t* Vt1, ushort_t* Plw) {
    const int qbase = bq * 64 + wave * 16;

    AState S;
    {
        const ushort_t* qp = qk + (rowbase + qbase + l15) * 2048 + h * 64 + l4 * 8;
        S.q0 = *(const bf16x8*)qp;
        S.q1 = *(const bf16x8*)(qp + 32);
    }
#pragma unroll
    for (int i = 0; i < 4; ++i) S.o[i] = (f32x4){0.f, 0.f, 0.f, 0.f};
    S.m = -INFINITY;
    S.l = 0.f;

    // prologue: stage tile 0 into buffer 0 (K rows + V^T rows, each 2x8 rows)
    glds16(gk, &Ks0[(wave * 16) * 64]);
    glds16(gk + (size_t)8 * 2048, &Ks0[(wave * 16 + 8) * 64]);
    glds16(gvt, &Vt0[(wave * 16) * 64]);
    glds16(gvt + (size_t)8 * 2048, &Vt0[(wave * 16 + 8) * 64]);
    __syncthreads();

    const int nt = bq + 1;
    for (int t = 0; t < nt; ++t) {
        ushort_t* Kc = (t & 1) ? Ks1 : Ks0;
        ushort_t* Vc = (t & 1) ? Vt1 : Vt0;
        ushort_t* Kn = (t & 1) ? Ks0 : Ks1;
        ushort_t* Vn = (t & 1) ? Vt0 : Vt1;
        if (t + 1 < nt) {
            const size_t koff = (size_t)(t + 1) * 64 * 2048;   // K: +64 token rows
            glds16(gk + koff, &Kn[(wave * 16) * 64]);
            glds16(gk + koff + (size_t)8 * 2048, &Kn[(wave * 16 + 8) * 64]);
            const size_t voff = (size_t)(t + 1) * 64;          // V^T: +64 key cols
            glds16(gvt + voff, &Vn[(wave * 16) * 64]);
            glds16(gvt + voff + (size_t)8 * 2048, &Vn[(wave * 16 + 8) * 64]);
        }
        if (t == bq)
            attn_tile<true>(S, Kc, Vc, Plw, l15, l4, wave * 16 + l15);
        else
            attn_tile<false>(S, Kc, Vc, Plw, l15, l4, 0);
        __syncthreads();   // next tile fully staged; old buffers free
    }

    // epilogue: normalize and store
    const float li0 = __shfl(S.l, l4 * 4 + 0);
    const float li1 = __shfl(S.l, l4 * 4 + 1);
    const float li2 = __shfl(S.l, l4 * 4 + 2);
    const float li3 = __shfl(S.l, l4 * 4 + 3);
#pragma unroll
    for (int r = 0; r < 4; ++r) {
        const int qr = qbase + l4 * 4 + r;
        const float li = (r == 0) ? li0 : (r == 1) ? li1 : (r == 2) ? li2 : li3;
        ushort_t* op = out + (rowbase + qr) * DM + h * 64 + l15;
#pragma unroll
        for (int dt = 0; dt < 4; ++dt)
            op[dt * 16] = f2bf(S.o[dt][r] / li);
    }
}

__global__ __launch_bounds__(256, 4) void attn_kernel(const ushort_t* __restrict__ qk,
                                                      const ushort_t* __restrict__ vt,
                                                      ushort_t* __restrict__ out) {
    __shared__ __attribute__((aligned(16))) ushort_t Ks[2][64 * 64];
    __shared__ __attribute__((aligned(16))) ushort_t Vt[2][64 * 64];
    __shared__ __attribute__((aligned(16))) ushort_t Pl[4][16 * 64];
    const int tid = threadIdx.x;
    const int wave = tid >> 6, lane = tid & 63;
    const int l15 = lane & 15, l4 = lane >> 4;
    const int bh = blockIdx.x;                  // 0..63
    const int b = bh >> 4, h = bh & 15;
    const int pair = blockIdx.y;                // 0..15
    const size_t rowbase = (size_t)b * SEQ;

    // staging lane geometry: row-within-8-group = lane>>3, pre-swizzled chunk
    const int krow = lane >> 3;                 // 0..7
    const int kch = (lane & 7) ^ krow;          // source 16B chunk (= dest chunk ^ row&7)
    const ushort_t* gk = qk + (rowbase + wave * 16 + krow) * 2048 + 1024 + h * 64 + kch * 8;
    const ushort_t* gvt = vt + ((size_t)b * 1024 + h * 64 + wave * 16 + krow) * 2048 + kch * 8;

    process_qblock(31 - pair, qk, out, rowbase, h, wave, l15, l4,
                   gk, gvt, Ks[0], Ks[1], Vt[0], Vt[1], Pl[wave]);
    process_qblock(pair, qk, out, rowbase, h, wave, l15, l4,
                   gk, gvt, Ks[0], Ks[1], Vt[0], Vt[1], Pl[wave]);
}

// ---------------- launcher ----------------
extern "C" void kernel_launch(void* const* d_in, const int* in_sizes, int n_in,
                              void* d_out, int out_size, void* d_ws, size_t ws_size,
                              hipStream_t stream) {
    const float* x     = (const float*)d_in[0];
    // d_in[1] = mask (causal, implemented analytically)
    const float* W_qkv = (const float*)d_in[2];
    const float* b_qkv = (const float*)d_in[3];
    const float* W_out = (const float*)d_in[4];
    const float* b_out = (const float*)d_in[5];
    float* out = (float*)d_out;

    char* ws = (char*)d_ws;
    ushort_t* xb    = (ushort_t*)(ws);                      // 16,777,216 B
    ushort_t* WqkvT = (ushort_t*)(ws + 16777216);           //  6,291,456 B
    ushort_t* WoutT = (ushort_t*)(ws + 23068672);           //  2,097,152 B
    ushort_t* qk    = (ushort_t*)(ws + 25165824);           // 33,554,432 B
    ushort_t* vt    = (ushort_t*)(ws + 58720256);           // 16,777,216 B
    ushort_t* attn  = (ushort_t*)(ws + 75497472);           // 16,777,216 B (total 92 MB)

    const int nx = BATCH * SEQ * DM;                        // 8,388,608
    cast_f32_bf16<<<nx / (256 * 4), 256, 0, stream>>>(x, xb, nx);
    transpose_cast<<<dim3(3 * DM / 32, DM / 32), dim3(32, 8), 0, stream>>>(W_qkv, WqkvT, DM, 3 * DM);
    transpose_cast<<<dim3(DM / 32, DM / 32), dim3(32, 8), 0, stream>>>(W_out, WoutT, DM, DM);

    // QKV projection: Q,K -> qk (stride 2048); V -> vt (transposed per head)
    gemm_qkv<<<dim3(3 * DM / 128, BATCH * SEQ / 128), 256, 0, stream>>>(
        xb, WqkvT, b_qkv, qk, vt, BATCH * SEQ, 3 * DM, DM);

    // attention: balanced sequential-pair blocks, 1024 = 4/CU all resident
    attn_kernel<<<dim3(BATCH * NH, SEQ / 128), 256, 0, stream>>>(qk, vt, attn);

    // output projection: [8192,1024] @ [1024,1024] -> f32 out
    gemm_abt<<<dim3(DM / 128, BATCH * SEQ / 128), 256, 0, stream>>>(
        attn, WoutT, b_out, out, BATCH * SEQ, DM, DM);
}

// Round 7
// 276.164 us; speedup vs baseline: 1.9264x; 1.0386x over previous
//
#include <hip/hip_runtime.h>

// ---------------- problem constants ----------------
#define BATCH 4
#define SEQ 2048
#define DM 1024
#define NH 16
#define SCALE 0.125f   // 64^-0.5
#define EXPC 0.18033688011112042f   // SCALE * log2(e)

typedef unsigned short ushort_t;
typedef short bf16x8 __attribute__((ext_vector_type(8)));
typedef float f32x4 __attribute__((ext_vector_type(4)));

__device__ __forceinline__ ushort_t f2bf(float f) {
    unsigned u = __float_as_uint(f);
    unsigned r = (u + 0x7FFFu + ((u >> 16) & 1u)) >> 16;
    return (ushort_t)r;
}

__device__ __forceinline__ unsigned cvtpk_bf16(float lo, float hi) {
    unsigned r;
    asm("v_cvt_pk_bf16_f32 %0, %1, %2" : "=v"(r) : "v"(lo), "v"(hi));
    return r;
}

__device__ __forceinline__ void glds16(const ushort_t* g, ushort_t* l) {
    __builtin_amdgcn_global_load_lds(
        (const __attribute__((address_space(1))) unsigned*)g,
        (__attribute__((address_space(3))) unsigned*)l, 16, 0, 0);
}

// ---------------- cast x: f32 -> bf16, 4 elems/thread ----------------
__global__ void cast_f32_bf16(const float* __restrict__ in, ushort_t* __restrict__ out, int n) {
    int i = (blockIdx.x * blockDim.x + threadIdx.x) * 4;
    if (i < n) {
        float4 v = *(const float4*)(in + i);
        ushort4 o;
        o.x = f2bf(v.x); o.y = f2bf(v.y); o.z = f2bf(v.z); o.w = f2bf(v.w);
        *(ushort4*)(out + i) = o;
    }
}

// ---------------- transpose+cast: in[K][N] f32 -> out[N][K] bf16 ----------------
__global__ void transpose_cast(const float* __restrict__ in, ushort_t* __restrict__ out,
                               int K, int N) {
    __shared__ float tile[32][33];
    int n0 = blockIdx.x * 32, k0 = blockIdx.y * 32;
    int x = threadIdx.x, y = threadIdx.y;   // blockDim = (32, 8)
#pragma unroll
    for (int j = 0; j < 32; j += 8)
        tile[y + j][x] = in[(size_t)(k0 + y + j) * N + n0 + x];
    __syncthreads();
#pragma unroll
    for (int j = 0; j < 32; j += 8)
        out[(size_t)(n0 + y + j) * K + k0 + x] = f2bf(tile[x][y + j]);
}

// ---------------- QKV GEMM (unchanged from round 6) ----------------
__global__ __launch_bounds__(256) void gemm_qkv(
    const ushort_t* __restrict__ A, const ushort_t* __restrict__ Bt,
    const float* __restrict__ bias, ushort_t* __restrict__ qk,
    ushort_t* __restrict__ vt, int M, int N, int K) {
    __shared__ __attribute__((aligned(16))) ushort_t As[128 * 64];
    __shared__ __attribute__((aligned(16))) ushort_t Bs[128 * 64];
    const int tid = threadIdx.x;
    const int lane = tid & 63, wave = tid >> 6;
    const int l15 = lane & 15, l4 = lane >> 4;
    const int m0 = blockIdx.y * 128, n0 = blockIdx.x * 128;
    const int wr = (wave >> 1) * 64, wc = (wave & 1) * 64;
    const int r8 = lane >> 3;
    const int kch = (lane & 7) ^ r8;
    const ushort_t* gA = A + (size_t)(m0 + wave * 32 + r8) * K + kch * 8;
    const ushort_t* gB = Bt + (size_t)(n0 + wave * 32 + r8) * K + kch * 8;
    const int r7 = l15 & 7;

    f32x4 acc[4][4];
#pragma unroll
    for (int i = 0; i < 4; ++i)
#pragma unroll
        for (int j = 0; j < 4; ++j) acc[i][j] = (f32x4){0.f, 0.f, 0.f, 0.f};

    for (int k0 = 0; k0 < K; k0 += 64) {
#pragma unroll
        for (int c = 0; c < 4; ++c) {
            glds16(gA + k0 + (size_t)(c * 8) * K, &As[(wave * 32 + c * 8) * 64]);
            glds16(gB + k0 + (size_t)(c * 8) * K, &Bs[(wave * 32 + c * 8) * 64]);
        }
        __syncthreads();
#pragma unroll
        for (int kh = 0; kh < 2; ++kh) {
            const int ch = ((kh * 4 + l4) ^ r7) * 8;
            bf16x8 a[4], b[4];
#pragma unroll
            for (int i = 0; i < 4; ++i) {
                a[i] = *(const bf16x8*)&As[(wr + i * 16 + l15) * 64 + ch];
                b[i] = *(const bf16x8*)&Bs[(wc + i * 16 + l15) * 64 + ch];
            }
#pragma unroll
            for (int mi = 0; mi < 4; ++mi)
#pragma unroll
                for (int ni = 0; ni < 4; ++ni)
                    acc[mi][ni] = __builtin_amdgcn_mfma_f32_16x16x32_bf16(
                        a[mi], b[ni], acc[mi][ni], 0, 0, 0);
        }
        __syncthreads();
    }

    if (n0 < 2048) {
#pragma unroll
        for (int mi = 0; mi < 4; ++mi)
#pragma unroll
            for (int ni = 0; ni < 4; ++ni) {
                const int col = n0 + wc + ni * 16 + l15;
                const float bv = bias[col];
#pragma unroll
                for (int r = 0; r < 4; ++r) {
                    const int row = m0 + wr + mi * 16 + l4 * 4 + r;
                    qk[(size_t)row * 2048 + col] = f2bf(acc[mi][ni][r] + bv);
                }
            }
    } else {
#pragma unroll
        for (int mi = 0; mi < 4; ++mi)
#pragma unroll
            for (int ni = 0; ni < 4; ++ni) {
                const int hdg = n0 + wc + ni * 16 + l15 - 2048;
                const float bv = bias[2048 + hdg];
                const int row0 = m0 + wr + mi * 16 + l4 * 4;
                const int bb = row0 >> 11, s0 = row0 & 2047;
                ushort4 pk;
                pk.x = f2bf(acc[mi][ni][0] + bv);
                pk.y = f2bf(acc[mi][ni][1] + bv);
                pk.z = f2bf(acc[mi][ni][2] + bv);
                pk.w = f2bf(acc[mi][ni][3] + bv);
                *(ushort4*)&vt[((size_t)bb * 1024 + hdg) * 2048 + s0] = pk;
            }
    }
}

// ---------------- out-projection GEMM (unchanged) ----------------
__global__ __launch_bounds__(256) void gemm_abt(
    const ushort_t* __restrict__ A, const ushort_t* __restrict__ Bt,
    const float* __restrict__ bias, float* __restrict__ Cout,
    int M, int N, int K) {
    __shared__ __attribute__((aligned(16))) ushort_t As[128 * 64];
    __shared__ __attribute__((aligned(16))) ushort_t Bs[128 * 64];
    const int tid = threadIdx.x;
    const int lane = tid & 63, wave = tid >> 6;
    const int l15 = lane & 15, l4 = lane >> 4;
    const int m0 = blockIdx.y * 128, n0 = blockIdx.x * 128;
    const int wr = (wave >> 1) * 64, wc = (wave & 1) * 64;
    const int r8 = lane >> 3;
    const int kch = (lane & 7) ^ r8;
    const ushort_t* gA = A + (size_t)(m0 + wave * 32 + r8) * K + kch * 8;
    const ushort_t* gB = Bt + (size_t)(n0 + wave * 32 + r8) * K + kch * 8;
    const int r7 = l15 & 7;

    f32x4 acc[4][4];
#pragma unroll
    for (int i = 0; i < 4; ++i)
#pragma unroll
        for (int j = 0; j < 4; ++j) acc[i][j] = (f32x4){0.f, 0.f, 0.f, 0.f};

    for (int k0 = 0; k0 < K; k0 += 64) {
#pragma unroll
        for (int c = 0; c < 4; ++c) {
            glds16(gA + k0 + (size_t)(c * 8) * K, &As[(wave * 32 + c * 8) * 64]);
            glds16(gB + k0 + (size_t)(c * 8) * K, &Bs[(wave * 32 + c * 8) * 64]);
        }
        __syncthreads();
#pragma unroll
        for (int kh = 0; kh < 2; ++kh) {
            const int ch = ((kh * 4 + l4) ^ r7) * 8;
            bf16x8 a[4], b[4];
#pragma unroll
            for (int i = 0; i < 4; ++i) {
                a[i] = *(const bf16x8*)&As[(wr + i * 16 + l15) * 64 + ch];
                b[i] = *(const bf16x8*)&Bs[(wc + i * 16 + l15) * 64 + ch];
            }
#pragma unroll
            for (int mi = 0; mi < 4; ++mi)
#pragma unroll
                for (int ni = 0; ni < 4; ++ni)
                    acc[mi][ni] = __builtin_amdgcn_mfma_f32_16x16x32_bf16(
                        a[mi], b[ni], acc[mi][ni], 0, 0, 0);
        }
        __syncthreads();
    }

#pragma unroll
    for (int mi = 0; mi < 4; ++mi)
#pragma unroll
        for (int ni = 0; ni < 4; ++ni)
#pragma unroll
            for (int r = 0; r < 4; ++r) {
                const int row = m0 + wr + mi * 16 + l4 * 4 + r;
                const int col = n0 + wc + ni * 16 + l15;
                Cout[(size_t)row * N + col] = acc[mi][ni][r] + bias[col];
            }
}

// ---------------- flash attention ----------------
// Wave owns 32 q-rows (two sequential 16-row states A,B sharing K/V frag
// reads). Block = 4 waves = 128 q-rows; pairing over 8 pairs -> nt = 2bq+2
// ALWAYS EVEN -> clean unroll-by-2 with static double-buffer pointers.
// Mask only the final tile pair. Defer check per-lane (no shuffles on the
// common path); l accumulated per-lane, reduced once in epilogue.
// Grid 512 = 2 blocks/CU (grid-bound) -> launch_bounds(256,2): VGPR<=256,
// no spill possible.
struct AState {
    bf16x8 q0, q1;
    f32x4 o[4];
    float m, l;
};

template <bool MASK>
__device__ __forceinline__ void softmax_state(const f32x4* z, AState& S,
                                              ushort_t* __restrict__ Plw,
                                              int l15, int l4, int rel) {
    float p[16];
    float pmax = -INFINITY;
#pragma unroll
    for (int kt = 0; kt < 4; ++kt)
#pragma unroll
        for (int r = 0; r < 4; ++r) {
            float v = z[kt][r];
            if (MASK) v = (kt * 16 + l4 * 4 + r > rel) ? -INFINITY : v;
            p[kt * 4 + r] = v;
            pmax = fmaxf(pmax, v);
        }
    // per-lane defer check (raw THR 64 == scaled 8); first tile (m=-inf)
    // always takes the rescale path.
    if (!__all(pmax - S.m <= 64.f)) {
        pmax = fmaxf(pmax, __shfl_xor(pmax, 16));
        pmax = fmaxf(pmax, __shfl_xor(pmax, 32));
        const float mnew = fmaxf(S.m, pmax);
        const float scl = __builtin_exp2f((S.m - mnew) * EXPC);  // 0 on first tile
        S.l *= scl;
        const float sc0 = __shfl(scl, l4 * 4 + 0);
        const float sc1 = __shfl(scl, l4 * 4 + 1);
        const float sc2 = __shfl(scl, l4 * 4 + 2);
        const float sc3 = __shfl(scl, l4 * 4 + 3);
#pragma unroll
        for (int dt = 0; dt < 4; ++dt) {
            S.o[dt][0] *= sc0; S.o[dt][1] *= sc1; S.o[dt][2] *= sc2; S.o[dt][3] *= sc3;
        }
        S.m = mnew;
    }
    const float mC = S.m * EXPC;
    float rsum = 0.f;
#pragma unroll
    for (int i = 0; i < 16; ++i) {
        p[i] = __builtin_exp2f(fmaf(p[i], EXPC, -mC));
        rsum += p[i];
    }
    S.l += rsum;                       // per-lane partial; reduced in epilogue
    const int pr7 = l15 & 7;
#pragma unroll
    for (int kt = 0; kt < 4; ++kt) {
        uint2 w;
        w.x = cvtpk_bf16(p[kt * 4 + 0], p[kt * 4 + 1]);
        w.y = cvtpk_bf16(p[kt * 4 + 2], p[kt * 4 + 3]);
        *(uint2*)&Plw[l15 * 64 + ((kt * 16 + l4 * 4) ^ (pr7 << 3))] = w;
    }
}

template <bool MASK>
__device__ __forceinline__ void tile2(const ushort_t* __restrict__ Ksb,
                                      const ushort_t* __restrict__ Vtb,
                                      ushort_t* __restrict__ PlA,
                                      ushort_t* __restrict__ PlB,
                                      AState& SA, AState& SB,
                                      int l15, int l4, int relA, int relB) {
    // QK^T (swapped) for both states, K-frags read ONCE
    f32x4 zA[4], zB[4];
    __builtin_amdgcn_s_setprio(1);
#pragma unroll
    for (int kt = 0; kt < 4; ++kt) {
        const int row = kt * 16 + l15, r7 = row & 7;
        bf16x8 ak0 = *(const bf16x8*)&Ksb[row * 64 + ((l4 ^ r7) * 8)];
        bf16x8 ak1 = *(const bf16x8*)&Ksb[row * 64 + (((4 + l4) ^ r7) * 8)];
        f32x4 z = {0.f, 0.f, 0.f, 0.f};
        z = __builtin_amdgcn_mfma_f32_16x16x32_bf16(ak0, SA.q0, z, 0, 0, 0);
        z = __builtin_amdgcn_mfma_f32_16x16x32_bf16(ak1, SA.q1, z, 0, 0, 0);
        zA[kt] = z;
        f32x4 y = {0.f, 0.f, 0.f, 0.f};
        y = __builtin_amdgcn_mfma_f32_16x16x32_bf16(ak0, SB.q0, y, 0, 0, 0);
        y = __builtin_amdgcn_mfma_f32_16x16x32_bf16(ak1, SB.q1, y, 0, 0, 0);
        zB[kt] = y;
    }
    __builtin_amdgcn_s_setprio(0);

    softmax_state<MASK>(zA, SA, PlA, l15, l4, relA);
    softmax_state<MASK>(zB, SB, PlB, l15, l4, relB);

    // PV for both states, V-frags read ONCE
    const int pr7 = l15 & 7;
    bf16x8 paA0 = *(const bf16x8*)&PlA[l15 * 64 + ((l4 ^ pr7) * 8)];
    bf16x8 paA1 = *(const bf16x8*)&PlA[l15 * 64 + (((4 + l4) ^ pr7) * 8)];
    bf16x8 paB0 = *(const bf16x8*)&PlB[l15 * 64 + ((l4 ^ pr7) * 8)];
    bf16x8 paB1 = *(const bf16x8*)&PlB[l15 * 64 + (((4 + l4) ^ pr7) * 8)];
    __builtin_amdgcn_s_setprio(1);
#pragma unroll
    for (int dt = 0; dt < 4; ++dt) {
        const int d = dt * 16 + l15, r7 = d & 7;
        bf16x8 bv0 = *(const bf16x8*)&Vtb[d * 64 + ((l4 ^ r7) * 8)];
        bf16x8 bv1 = *(const bf16x8*)&Vtb[d * 64 + (((4 + l4) ^ r7) * 8)];
        SA.o[dt] = __builtin_amdgcn_mfma_f32_16x16x32_bf16(paA0, bv0, SA.o[dt], 0, 0, 0);
        SA.o[dt] = __builtin_amdgcn_mfma_f32_16x16x32_bf16(paA1, bv1, SA.o[dt], 0, 0, 0);
        SB.o[dt] = __builtin_amdgcn_mfma_f32_16x16x32_bf16(paB0, bv0, SB.o[dt], 0, 0, 0);
        SB.o[dt] = __builtin_amdgcn_mfma_f32_16x16x32_bf16(paB1, bv1, SB.o[dt], 0, 0, 0);
    }
    __builtin_amdgcn_s_setprio(0);
}

__device__ __forceinline__ void attn_store(const AState& S, ushort_t* out, size_t rowbase,
                                           int qbase, int h, int l15, int l4) {
    float lt = S.l;
    lt += __shfl_xor(lt, 16);
    lt += __shfl_xor(lt, 32);
    const float li0 = __shfl(lt, l4 * 4 + 0);
    const float li1 = __shfl(lt, l4 * 4 + 1);
    const float li2 = __shfl(lt, l4 * 4 + 2);
    const float li3 = __shfl(lt, l4 * 4 + 3);
#pragma unroll
    for (int r = 0; r < 4; ++r) {
        const int qr = qbase + l4 * 4 + r;
        const float li = (r == 0) ? li0 : (r == 1) ? li1 : (r == 2) ? li2 : li3;
        ushort_t* op = out + (rowbase + qr) * DM + h * 64 + l15;
#pragma unroll
        for (int dt = 0; dt < 4; ++dt)
            op[dt * 16] = f2bf(S.o[dt][r] / li);
    }
}

__global__ __launch_bounds__(256, 2) void attn_kernel(const ushort_t* __restrict__ qk,
                                                      const ushort_t* __restrict__ vt,
                                                      ushort_t* __restrict__ out) {
    __shared__ __attribute__((aligned(16))) ushort_t Ks[2][64 * 64];
    __shared__ __attribute__((aligned(16))) ushort_t Vt[2][64 * 64];
    __shared__ __attribute__((aligned(16))) ushort_t Pl[8][16 * 64];
    const int tid = threadIdx.x;
    const int wave = tid >> 6, lane = tid & 63;
    const int l15 = lane & 15, l4 = lane >> 4;
    const int bh = blockIdx.x;                  // 0..63
    const int b = bh >> 4, h = bh & 15;
    const int pair = blockIdx.y;                // 0..7
    const size_t rowbase = (size_t)b * SEQ;

    // staging lane geometry (wave stages K rows / V^T rows [wave*16, +16))
    const int krow = lane >> 3;
    const int kch = (lane & 7) ^ krow;          // pre-swizzled source chunk
    const ushort_t* gk = qk + (rowbase + wave * 16 + krow) * 2048 + 1024 + h * 64 + kch * 8;
    const ushort_t* gvt = vt + ((size_t)b * 1024 + h * 64 + wave * 16 + krow) * 2048 + kch * 8;
    ushort_t* KsW0 = &Ks[0][(wave * 16) * 64];
    ushort_t* KsW1 = &Ks[1][(wave * 16) * 64];
    ushort_t* VtW0 = &Vt[0][(wave * 16) * 64];
    ushort_t* VtW1 = &Vt[1][(wave * 16) * 64];
    ushort_t* PlA = Pl[wave * 2];
    ushort_t* PlB = Pl[wave * 2 + 1];

#pragma unroll 1
    for (int half = 0; half < 2; ++half) {
        const int bq = half ? pair : (15 - pair);   // heavy then light, balanced
        const int qsA = bq * 128 + wave * 32;
        const int qsB = qsA + 16;
        const int nt = 2 * bq + 2;                  // always even

        AState SA, SB;
        {
            const ushort_t* qp = qk + (rowbase + qsA + l15) * 2048 + h * 64 + l4 * 8;
            SA.q0 = *(const bf16x8*)qp;
            SA.q1 = *(const bf16x8*)(qp + 32);
            const ushort_t* qp2 = qp + (size_t)16 * 2048;
            SB.q0 = *(const bf16x8*)qp2;
            SB.q1 = *(const bf16x8*)(qp2 + 32);
        }
#pragma unroll
        for (int i = 0; i < 4; ++i) {
            SA.o[i] = (f32x4){0.f, 0.f, 0.f, 0.f};
            SB.o[i] = (f32x4){0.f, 0.f, 0.f, 0.f};
        }
        SA.m = -INFINITY; SA.l = 0.f;
        SB.m = -INFINITY; SB.l = 0.f;

        // prologue: stage tile 0 -> buf0
        glds16(gk, KsW0);
        glds16(gk + (size_t)8 * 2048, KsW0 + 8 * 64);
        glds16(gvt, VtW0);
        glds16(gvt + (size_t)8 * 2048, VtW0 + 8 * 64);
        __syncthreads();

        const ushort_t* gks = gk + (size_t)64 * 2048;
        const ushort_t* gvs = gvt + 64;
        int t = 0;
        for (; t + 2 < nt; t += 2) {
            // tile t in buf0 (no mask), prefetch t+1 -> buf1
            glds16(gks, KsW1);
            glds16(gks + (size_t)8 * 2048, KsW1 + 8 * 64);
            glds16(gvs, VtW1);
            glds16(gvs + (size_t)8 * 2048, VtW1 + 8 * 64);
            gks += (size_t)64 * 2048; gvs += 64;
            tile2<false>(Ks[0], Vt[0], PlA, PlB, SA, SB, l15, l4, 0, 0);
            __syncthreads();
            // tile t+1 in buf1 (no mask), prefetch t+2 -> buf0
            glds16(gks, KsW0);
            glds16(gks + (size_t)8 * 2048, KsW0 + 8 * 64);
            glds16(gvs, VtW0);
            glds16(gvs + (size_t)8 * 2048, VtW0 + 8 * 64);
            gks += (size_t)64 * 2048; gvs += 64;
            tile2<false>(Ks[1], Vt[1], PlA, PlB, SA, SB, l15, l4, 0, 0);
            __syncthreads();
        }
        // final masked pair: tiles nt-2 (buf0) and nt-1 (buf1)
        glds16(gks, KsW1);
        glds16(gks + (size_t)8 * 2048, KsW1 + 8 * 64);
        glds16(gvs, VtW1);
        glds16(gvs + (size_t)8 * 2048, VtW1 + 8 * 64);
        tile2<true>(Ks[0], Vt[0], PlA, PlB, SA, SB, l15, l4,
                    qsA + l15 - (nt - 2) * 64, qsB + l15 - (nt - 2) * 64);
        __syncthreads();
        tile2<true>(Ks[1], Vt[1], PlA, PlB, SA, SB, l15, l4,
                    qsA + l15 - (nt - 1) * 64, qsB + l15 - (nt - 1) * 64);

        attn_store(SA, out, rowbase, qsA, h, l15, l4);
        attn_store(SB, out, rowbase, qsB, h, l15, l4);
        __syncthreads();   // buffers free before next half's prologue
    }
}

// ---------------- launcher ----------------
extern "C" void kernel_launch(void* const* d_in, const int* in_sizes, int n_in,
                              void* d_out, int out_size, void* d_ws, size_t ws_size,
                              hipStream_t stream) {
    const float* x     = (const float*)d_in[0];
    // d_in[1] = mask (causal, implemented analytically)
    const float* W_qkv = (const float*)d_in[2];
    const float* b_qkv = (const float*)d_in[3];
    const float* W_out = (const float*)d_in[4];
    const float* b_out = (const float*)d_in[5];
    float* out = (float*)d_out;

    char* ws = (char*)d_ws;
    ushort_t* xb    = (ushort_t*)(ws);                      // 16,777,216 B
    ushort_t* WqkvT = (ushort_t*)(ws + 16777216);           //  6,291,456 B
    ushort_t* WoutT = (ushort_t*)(ws + 23068672);           //  2,097,152 B
    ushort_t* qk    = (ushort_t*)(ws + 25165824);           // 33,554,432 B
    ushort_t* vt    = (ushort_t*)(ws + 58720256);           // 16,777,216 B
    ushort_t* attn  = (ushort_t*)(ws + 75497472);           // 16,777,216 B (total 92 MB)

    const int nx = BATCH * SEQ * DM;                        // 8,388,608
    cast_f32_bf16<<<nx / (256 * 4), 256, 0, stream>>>(x, xb, nx);
    transpose_cast<<<dim3(3 * DM / 32, DM / 32), dim3(32, 8), 0, stream>>>(W_qkv, WqkvT, DM, 3 * DM);
    transpose_cast<<<dim3(DM / 32, DM / 32), dim3(32, 8), 0, stream>>>(W_out, WoutT, DM, DM);

    // QKV projection: Q,K -> qk (stride 2048); V -> vt (transposed per head)
    gemm_qkv<<<dim3(3 * DM / 128, BATCH * SEQ / 128), 256, 0, stream>>>(
        xb, WqkvT, b_qkv, qk, vt, BATCH * SEQ, 3 * DM, DM);

    // attention: 512 blocks (64 bh x 8 pairs), 128 q-rows/block, balanced
    attn_kernel<<<dim3(BATCH * NH, 8), 256, 0, stream>>>(qk, vt, attn);

    // output projection: [8192,1024] @ [1024,1024] -> f32 out
    gemm_abt<<<dim3(DM / 128, BATCH * SEQ / 128), 256, 0, stream>>>(
        attn, WoutT, b_out, out, BATCH * SEQ, DM, DM);
}

// Round 8
// 271.282 us; speedup vs baseline: 1.9611x; 1.0180x over previous
//
#include <hip/hip_runtime.h>

// ---------------- problem constants ----------------
#define BATCH 4
#define SEQ 2048
#define DM 1024
#define NH 16
#define SCALE 0.125f   // 64^-0.5
#define EXPC 0.18033688011112042f   // SCALE * log2(e)

typedef unsigned short ushort_t;
typedef short bf16x8 __attribute__((ext_vector_type(8)));
typedef float f32x4 __attribute__((ext_vector_type(4)));

__device__ __forceinline__ ushort_t f2bf(float f) {
    unsigned u = __float_as_uint(f);
    unsigned r = (u + 0x7FFFu + ((u >> 16) & 1u)) >> 16;
    return (ushort_t)r;
}

__device__ __forceinline__ unsigned cvtpk_bf16(float lo, float hi) {
    unsigned r;
    asm("v_cvt_pk_bf16_f32 %0, %1, %2" : "=v"(r) : "v"(lo), "v"(hi));
    return r;
}

__device__ __forceinline__ void glds16(const ushort_t* g, ushort_t* l) {
    __builtin_amdgcn_global_load_lds(
        (const __attribute__((address_space(1))) unsigned*)g,
        (__attribute__((address_space(3))) unsigned*)l, 16, 0, 0);
}

// ---------------- unified prep: cast x + transpose both weights ----------------
// grid 12288 x 256: [0,8192) cast x; [8192,11264) W_qkv^T; [11264,12288) W_out^T
__global__ __launch_bounds__(256) void prep(
    const float* __restrict__ x, ushort_t* __restrict__ xb,
    const float* __restrict__ Wqkv, ushort_t* __restrict__ WqkvT,
    const float* __restrict__ Wout, ushort_t* __restrict__ WoutT) {
    __shared__ float tile[32][33];
    const int bid = blockIdx.x, tid = threadIdx.x;
    if (bid < 8192) {
        const int i = bid * 1024 + tid * 4;
        float4 v = *(const float4*)(x + i);
        ushort4 o;
        o.x = f2bf(v.x); o.y = f2bf(v.y); o.z = f2bf(v.z); o.w = f2bf(v.w);
        *(ushort4*)(xb + i) = o;
        return;
    }
    const float* in;
    ushort_t* outp;
    int K = 1024, N, n0, k0;
    if (bid < 11264) {
        const int t = bid - 8192;
        in = Wqkv; outp = WqkvT; N = 3072;
        n0 = (t % 96) * 32; k0 = (t / 96) * 32;
    } else {
        const int t = bid - 11264;
        in = Wout; outp = WoutT; N = 1024;
        n0 = (t & 31) * 32; k0 = (t >> 5) * 32;
    }
    const int tx = tid & 31, ty = tid >> 5;   // 32 x 8
#pragma unroll
    for (int j = 0; j < 32; j += 8)
        tile[ty + j][tx] = in[(size_t)(k0 + ty + j) * N + n0 + tx];
    __syncthreads();
#pragma unroll
    for (int j = 0; j < 32; j += 8)
        outp[(size_t)(n0 + ty + j) * K + k0 + tx] = f2bf(tile[tx][ty + j]);
}

// ---------------- block swizzle: XCD bijective chunk + 8-row groups ----------------
// XCD k owns a contiguous chunk; within it, 8 consecutive m-tiles share each
// B-panel (m fastest in groups of 8) -> per-XCD L2 working set ~2.3 MB.
__device__ __forceinline__ void swz_tile(int flat, int nbm, int nbn, int& m0, int& n0) {
    const int nwg = nbm * nbn;
    const int cpx = nwg >> 3;
    const int swz = (flat & 7) * cpx + (flat >> 3);
    const int gsz = nbn << 3;
    const int grp = swz / gsz;
    const int rem = swz - grp * gsz;
    m0 = ((grp << 3) + (rem & 7)) << 7;
    n0 = (rem >> 3) << 7;
}

// ---------------- QKV GEMM (128x128, BK=64, glds16, XOR swizzle) ----------------
__global__ __launch_bounds__(256) void gemm_qkv(
    const ushort_t* __restrict__ A, const ushort_t* __restrict__ Bt,
    const float* __restrict__ bias, ushort_t* __restrict__ qk,
    ushort_t* __restrict__ vt, int M, int N, int K) {
    __shared__ __attribute__((aligned(16))) ushort_t As[128 * 64];
    __shared__ __attribute__((aligned(16))) ushort_t Bs[128 * 64];
    const int tid = threadIdx.x;
    const int lane = tid & 63, wave = tid >> 6;
    const int l15 = lane & 15, l4 = lane >> 4;
    int m0, n0;
    swz_tile((int)blockIdx.x, M >> 7, N >> 7, m0, n0);
    const int wr = (wave >> 1) * 64, wc = (wave & 1) * 64;
    const int r8 = lane >> 3;
    const int kch = (lane & 7) ^ r8;
    const ushort_t* gA = A + (size_t)(m0 + wave * 32 + r8) * K + kch * 8;
    const ushort_t* gB = Bt + (size_t)(n0 + wave * 32 + r8) * K + kch * 8;
    const int r7 = l15 & 7;

    f32x4 acc[4][4];
#pragma unroll
    for (int i = 0; i < 4; ++i)
#pragma unroll
        for (int j = 0; j < 4; ++j) acc[i][j] = (f32x4){0.f, 0.f, 0.f, 0.f};

    for (int k0 = 0; k0 < K; k0 += 64) {
#pragma unroll
        for (int c = 0; c < 4; ++c) {
            glds16(gA + k0 + (size_t)(c * 8) * K, &As[(wave * 32 + c * 8) * 64]);
            glds16(gB + k0 + (size_t)(c * 8) * K, &Bs[(wave * 32 + c * 8) * 64]);
        }
        __syncthreads();
#pragma unroll
        for (int kh = 0; kh < 2; ++kh) {
            const int ch = ((kh * 4 + l4) ^ r7) * 8;
            bf16x8 a[4], b[4];
#pragma unroll
            for (int i = 0; i < 4; ++i) {
                a[i] = *(const bf16x8*)&As[(wr + i * 16 + l15) * 64 + ch];
                b[i] = *(const bf16x8*)&Bs[(wc + i * 16 + l15) * 64 + ch];
            }
#pragma unroll
            for (int mi = 0; mi < 4; ++mi)
#pragma unroll
                for (int ni = 0; ni < 4; ++ni)
                    acc[mi][ni] = __builtin_amdgcn_mfma_f32_16x16x32_bf16(
                        a[mi], b[ni], acc[mi][ni], 0, 0, 0);
        }
        __syncthreads();
    }

    if (n0 < 2048) {
#pragma unroll
        for (int mi = 0; mi < 4; ++mi)
#pragma unroll
            for (int ni = 0; ni < 4; ++ni) {
                const int col = n0 + wc + ni * 16 + l15;
                const float bv = bias[col];
#pragma unroll
                for (int r = 0; r < 4; ++r) {
                    const int row = m0 + wr + mi * 16 + l4 * 4 + r;
                    qk[(size_t)row * 2048 + col] = f2bf(acc[mi][ni][r] + bv);
                }
            }
    } else {
#pragma unroll
        for (int mi = 0; mi < 4; ++mi)
#pragma unroll
            for (int ni = 0; ni < 4; ++ni) {
                const int hdg = n0 + wc + ni * 16 + l15 - 2048;
                const float bv = bias[2048 + hdg];
                const int row0 = m0 + wr + mi * 16 + l4 * 4;
                const int bb = row0 >> 11, s0 = row0 & 2047;
                ushort4 pk;
                pk.x = f2bf(acc[mi][ni][0] + bv);
                pk.y = f2bf(acc[mi][ni][1] + bv);
                pk.z = f2bf(acc[mi][ni][2] + bv);
                pk.w = f2bf(acc[mi][ni][3] + bv);
                *(ushort4*)&vt[((size_t)bb * 1024 + hdg) * 2048 + s0] = pk;
            }
    }
}

// ---------------- out-projection GEMM (swizzled blocks) ----------------
__global__ __launch_bounds__(256) void gemm_abt(
    const ushort_t* __restrict__ A, const ushort_t* __restrict__ Bt,
    const float* __restrict__ bias, float* __restrict__ Cout,
    int M, int N, int K) {
    __shared__ __attribute__((aligned(16))) ushort_t As[128 * 64];
    __shared__ __attribute__((aligned(16))) ushort_t Bs[128 * 64];
    const int tid = threadIdx.x;
    const int lane = tid & 63, wave = tid >> 6;
    const int l15 = lane & 15, l4 = lane >> 4;
    int m0, n0;
    swz_tile((int)blockIdx.x, M >> 7, N >> 7, m0, n0);
    const int wr = (wave >> 1) * 64, wc = (wave & 1) * 64;
    const int r8 = lane >> 3;
    const int kch = (lane & 7) ^ r8;
    const ushort_t* gA = A + (size_t)(m0 + wave * 32 + r8) * K + kch * 8;
    const ushort_t* gB = Bt + (size_t)(n0 + wave * 32 + r8) * K + kch * 8;
    const int r7 = l15 & 7;

    f32x4 acc[4][4];
#pragma unroll
    for (int i = 0; i < 4; ++i)
#pragma unroll
        for (int j = 0; j < 4; ++j) acc[i][j] = (f32x4){0.f, 0.f, 0.f, 0.f};

    for (int k0 = 0; k0 < K; k0 += 64) {
#pragma unroll
        for (int c = 0; c < 4; ++c) {
            glds16(gA + k0 + (size_t)(c * 8) * K, &As[(wave * 32 + c * 8) * 64]);
            glds16(gB + k0 + (size_t)(c * 8) * K, &Bs[(wave * 32 + c * 8) * 64]);
        }
        __syncthreads();
#pragma unroll
        for (int kh = 0; kh < 2; ++kh) {
            const int ch = ((kh * 4 + l4) ^ r7) * 8;
            bf16x8 a[4], b[4];
#pragma unroll
            for (int i = 0; i < 4; ++i) {
                a[i] = *(const bf16x8*)&As[(wr + i * 16 + l15) * 64 + ch];
                b[i] = *(const bf16x8*)&Bs[(wc + i * 16 + l15) * 64 + ch];
            }
#pragma unroll
            for (int mi = 0; mi < 4; ++mi)
#pragma unroll
                for (int ni = 0; ni < 4; ++ni)
                    acc[mi][ni] = __builtin_amdgcn_mfma_f32_16x16x32_bf16(
                        a[mi], b[ni], acc[mi][ni], 0, 0, 0);
        }
        __syncthreads();
    }

#pragma unroll
    for (int mi = 0; mi < 4; ++mi)
#pragma unroll
        for (int ni = 0; ni < 4; ++ni)
#pragma unroll
            for (int r = 0; r < 4; ++r) {
                const int row = m0 + wr + mi * 16 + l4 * 4 + r;
                const int col = n0 + wc + ni * 16 + l15;
                Cout[(size_t)row * N + col] = acc[mi][ni][r] + bias[col];
            }
}

// ---------------- flash attention (unchanged from round 7) ----------------
struct AState {
    bf16x8 q0, q1;
    f32x4 o[4];
    float m, l;
};

template <bool MASK>
__device__ __forceinline__ void softmax_state(const f32x4* z, AState& S,
                                              ushort_t* __restrict__ Plw,
                                              int l15, int l4, int rel) {
    float p[16];
    float pmax = -INFINITY;
#pragma unroll
    for (int kt = 0; kt < 4; ++kt)
#pragma unroll
        for (int r = 0; r < 4; ++r) {
            float v = z[kt][r];
            if (MASK) v = (kt * 16 + l4 * 4 + r > rel) ? -INFINITY : v;
            p[kt * 4 + r] = v;
            pmax = fmaxf(pmax, v);
        }
    if (!__all(pmax - S.m <= 64.f)) {
        pmax = fmaxf(pmax, __shfl_xor(pmax, 16));
        pmax = fmaxf(pmax, __shfl_xor(pmax, 32));
        const float mnew = fmaxf(S.m, pmax);
        const float scl = __builtin_exp2f((S.m - mnew) * EXPC);  // 0 on first tile
        S.l *= scl;
        const float sc0 = __shfl(scl, l4 * 4 + 0);
        const float sc1 = __shfl(scl, l4 * 4 + 1);
        const float sc2 = __shfl(scl, l4 * 4 + 2);
        const float sc3 = __shfl(scl, l4 * 4 + 3);
#pragma unroll
        for (int dt = 0; dt < 4; ++dt) {
            S.o[dt][0] *= sc0; S.o[dt][1] *= sc1; S.o[dt][2] *= sc2; S.o[dt][3] *= sc3;
        }
        S.m = mnew;
    }
    const float mC = S.m * EXPC;
    float rsum = 0.f;
#pragma unroll
    for (int i = 0; i < 16; ++i) {
        p[i] = __builtin_exp2f(fmaf(p[i], EXPC, -mC));
        rsum += p[i];
    }
    S.l += rsum;
    const int pr7 = l15 & 7;
#pragma unroll
    for (int kt = 0; kt < 4; ++kt) {
        uint2 w;
        w.x = cvtpk_bf16(p[kt * 4 + 0], p[kt * 4 + 1]);
        w.y = cvtpk_bf16(p[kt * 4 + 2], p[kt * 4 + 3]);
        *(uint2*)&Plw[l15 * 64 + ((kt * 16 + l4 * 4) ^ (pr7 << 3))] = w;
    }
}

template <bool MASK>
__device__ __forceinline__ void tile2(const ushort_t* __restrict__ Ksb,
                                      const ushort_t* __restrict__ Vtb,
                                      ushort_t* __restrict__ PlA,
                                      ushort_t* __restrict__ PlB,
                                      AState& SA, AState& SB,
                                      int l15, int l4, int relA, int relB) {
    f32x4 zA[4], zB[4];
    __builtin_amdgcn_s_setprio(1);
#pragma unroll
    for (int kt = 0; kt < 4; ++kt) {
        const int row = kt * 16 + l15, r7 = row & 7;
        bf16x8 ak0 = *(const bf16x8*)&Ksb[row * 64 + ((l4 ^ r7) * 8)];
        bf16x8 ak1 = *(const bf16x8*)&Ksb[row * 64 + (((4 + l4) ^ r7) * 8)];
        f32x4 z = {0.f, 0.f, 0.f, 0.f};
        z = __builtin_amdgcn_mfma_f32_16x16x32_bf16(ak0, SA.q0, z, 0, 0, 0);
        z = __builtin_amdgcn_mfma_f32_16x16x32_bf16(ak1, SA.q1, z, 0, 0, 0);
        zA[kt] = z;
        f32x4 y = {0.f, 0.f, 0.f, 0.f};
        y = __builtin_amdgcn_mfma_f32_16x16x32_bf16(ak0, SB.q0, y, 0, 0, 0);
        y = __builtin_amdgcn_mfma_f32_16x16x32_bf16(ak1, SB.q1, y, 0, 0, 0);
        zB[kt] = y;
    }
    __builtin_amdgcn_s_setprio(0);

    softmax_state<MASK>(zA, SA, PlA, l15, l4, relA);
    softmax_state<MASK>(zB, SB, PlB, l15, l4, relB);

    const int pr7 = l15 & 7;
    bf16x8 paA0 = *(const bf16x8*)&PlA[l15 * 64 + ((l4 ^ pr7) * 8)];
    bf16x8 paA1 = *(const bf16x8*)&PlA[l15 * 64 + (((4 + l4) ^ pr7) * 8)];
    bf16x8 paB0 = *(const bf16x8*)&PlB[l15 * 64 + ((l4 ^ pr7) * 8)];
    bf16x8 paB1 = *(const bf16x8*)&PlB[l15 * 64 + (((4 + l4) ^ pr7) * 8)];
    __builtin_amdgcn_s_setprio(1);
#pragma unroll
    for (int dt = 0; dt < 4; ++dt) {
        const int d = dt * 16 + l15, r7 = d & 7;
        bf16x8 bv0 = *(const bf16x8*)&Vtb[d * 64 + ((l4 ^ r7) * 8)];
        bf16x8 bv1 = *(const bf16x8*)&Vtb[d * 64 + (((4 + l4) ^ r7) * 8)];
        SA.o[dt] = __builtin_amdgcn_mfma_f32_16x16x32_bf16(paA0, bv0, SA.o[dt], 0, 0, 0);
        SA.o[dt] = __builtin_amdgcn_mfma_f32_16x16x32_bf16(paA1, bv1, SA.o[dt], 0, 0, 0);
        SB.o[dt] = __builtin_amdgcn_mfma_f32_16x16x32_bf16(paB0, bv0, SB.o[dt], 0, 0, 0);
        SB.o[dt] = __builtin_amdgcn_mfma_f32_16x16x32_bf16(paB1, bv1, SB.o[dt], 0, 0, 0);
    }
    __builtin_amdgcn_s_setprio(0);
}

__device__ __forceinline__ void attn_store(const AState& S, ushort_t* out, size_t rowbase,
                                           int qbase, int h, int l15, int l4) {
    float lt = S.l;
    lt += __shfl_xor(lt, 16);
    lt += __shfl_xor(lt, 32);
    const float li0 = __shfl(lt, l4 * 4 + 0);
    const float li1 = __shfl(lt, l4 * 4 + 1);
    const float li2 = __shfl(lt, l4 * 4 + 2);
    const float li3 = __shfl(lt, l4 * 4 + 3);
#pragma unroll
    for (int r = 0; r < 4; ++r) {
        const int qr = qbase + l4 * 4 + r;
        const float li = (r == 0) ? li0 : (r == 1) ? li1 : (r == 2) ? li2 : li3;
        ushort_t* op = out + (rowbase + qr) * DM + h * 64 + l15;
#pragma unroll
        for (int dt = 0; dt < 4; ++dt)
            op[dt * 16] = f2bf(S.o[dt][r] / li);
    }
}

__global__ __launch_bounds__(256, 2) void attn_kernel(const ushort_t* __restrict__ qk,
                                                      const ushort_t* __restrict__ vt,
                                                      ushort_t* __restrict__ out) {
    __shared__ __attribute__((aligned(16))) ushort_t Ks[2][64 * 64];
    __shared__ __attribute__((aligned(16))) ushort_t Vt[2][64 * 64];
    __shared__ __attribute__((aligned(16))) ushort_t Pl[8][16 * 64];
    const int tid = threadIdx.x;
    const int wave = tid >> 6, lane = tid & 63;
    const int l15 = lane & 15, l4 = lane >> 4;
    const int bh = blockIdx.x;                  // 0..63
    const int b = bh >> 4, h = bh & 15;
    const int pair = blockIdx.y;                // 0..7
    const size_t rowbase = (size_t)b * SEQ;

    const int krow = lane >> 3;
    const int kch = (lane & 7) ^ krow;          // pre-swizzled source chunk
    const ushort_t* gk = qk + (rowbase + wave * 16 + krow) * 2048 + 1024 + h * 64 + kch * 8;
    const ushort_t* gvt = vt + ((size_t)b * 1024 + h * 64 + wave * 16 + krow) * 2048 + kch * 8;
    ushort_t* KsW0 = &Ks[0][(wave * 16) * 64];
    ushort_t* KsW1 = &Ks[1][(wave * 16) * 64];
    ushort_t* VtW0 = &Vt[0][(wave * 16) * 64];
    ushort_t* VtW1 = &Vt[1][(wave * 16) * 64];
    ushort_t* PlA = Pl[wave * 2];
    ushort_t* PlB = Pl[wave * 2 + 1];

#pragma unroll 1
    for (int half = 0; half < 2; ++half) {
        const int bq = half ? pair : (15 - pair);
        const int qsA = bq * 128 + wave * 32;
        const int qsB = qsA + 16;
        const int nt = 2 * bq + 2;                  // always even

        AState SA, SB;
        {
            const ushort_t* qp = qk + (rowbase + qsA + l15) * 2048 + h * 64 + l4 * 8;
            SA.q0 = *(const bf16x8*)qp;
            SA.q1 = *(const bf16x8*)(qp + 32);
            const ushort_t* qp2 = qp + (size_t)16 * 2048;
            SB.q0 = *(const bf16x8*)qp2;
            SB.q1 = *(const bf16x8*)(qp2 + 32);
        }
#pragma unroll
        for (int i = 0; i < 4; ++i) {
            SA.o[i] = (f32x4){0.f, 0.f, 0.f, 0.f};
            SB.o[i] = (f32x4){0.f, 0.f, 0.f, 0.f};
        }
        SA.m = -INFINITY; SA.l = 0.f;
        SB.m = -INFINITY; SB.l = 0.f;

        glds16(gk, KsW0);
        glds16(gk + (size_t)8 * 2048, KsW0 + 8 * 64);
        glds16(gvt, VtW0);
        glds16(gvt + (size_t)8 * 2048, VtW0 + 8 * 64);
        __syncthreads();

        const ushort_t* gks = gk + (size_t)64 * 2048;
        const ushort_t* gvs = gvt + 64;
        int t = 0;
        for (; t + 2 < nt; t += 2) {
            glds16(gks, KsW1);
            glds16(gks + (size_t)8 * 2048, KsW1 + 8 * 64);
            glds16(gvs, VtW1);
            glds16(gvs + (size_t)8 * 2048, VtW1 + 8 * 64);
            gks += (size_t)64 * 2048; gvs += 64;
            tile2<false>(Ks[0], Vt[0], PlA, PlB, SA, SB, l15, l4, 0, 0);
            __syncthreads();
            glds16(gks, KsW0);
            glds16(gks + (size_t)8 * 2048, KsW0 + 8 * 64);
            glds16(gvs, VtW0);
            glds16(gvs + (size_t)8 * 2048, VtW0 + 8 * 64);
            gks += (size_t)64 * 2048; gvs += 64;
            tile2<false>(Ks[1], Vt[1], PlA, PlB, SA, SB, l15, l4, 0, 0);
            __syncthreads();
        }
        glds16(gks, KsW1);
        glds16(gks + (size_t)8 * 2048, KsW1 + 8 * 64);
        glds16(gvs, VtW1);
        glds16(gvs + (size_t)8 * 2048, VtW1 + 8 * 64);
        tile2<true>(Ks[0], Vt[0], PlA, PlB, SA, SB, l15, l4,
                    qsA + l15 - (nt - 2) * 64, qsB + l15 - (nt - 2) * 64);
        __syncthreads();
        tile2<true>(Ks[1], Vt[1], PlA, PlB, SA, SB, l15, l4,
                    qsA + l15 - (nt - 1) * 64, qsB + l15 - (nt - 1) * 64);

        attn_store(SA, out, rowbase, qsA, h, l15, l4);
        attn_store(SB, out, rowbase, qsB, h, l15, l4);
        __syncthreads();
    }
}

// ---------------- launcher ----------------
extern "C" void kernel_launch(void* const* d_in, const int* in_sizes, int n_in,
                              void* d_out, int out_size, void* d_ws, size_t ws_size,
                              hipStream_t stream) {
    const float* x     = (const float*)d_in[0];
    // d_in[1] = mask (causal, implemented analytically)
    const float* W_qkv = (const float*)d_in[2];
    const float* b_qkv = (const float*)d_in[3];
    const float* W_out = (const float*)d_in[4];
    const float* b_out = (const float*)d_in[5];
    float* out = (float*)d_out;

    char* ws = (char*)d_ws;
    ushort_t* xb    = (ushort_t*)(ws);                      // 16,777,216 B
    ushort_t* WqkvT = (ushort_t*)(ws + 16777216);           //  6,291,456 B
    ushort_t* WoutT = (ushort_t*)(ws + 23068672);           //  2,097,152 B
    ushort_t* qk    = (ushort_t*)(ws + 25165824);           // 33,554,432 B
    ushort_t* vt    = (ushort_t*)(ws + 58720256);           // 16,777,216 B
    ushort_t* attn  = (ushort_t*)(ws + 75497472);           // 16,777,216 B (total 92 MB)

    // fused prep: cast x + transpose W_qkv + transpose W_out
    prep<<<12288, 256, 0, stream>>>(x, xb, W_qkv, WqkvT, W_out, WoutT);

    // QKV projection: Q,K -> qk (stride 2048); V -> vt (transposed per head)
    gemm_qkv<<<1536, 256, 0, stream>>>(xb, WqkvT, b_qkv, qk, vt,
                                       BATCH * SEQ, 3 * DM, DM);

    // attention: 512 blocks (64 bh x 8 pairs), 128 q-rows/block, balanced
    attn_kernel<<<dim3(BATCH * NH, 8), 256, 0, stream>>>(qk, vt, attn);

    // output projection: [8192,1024] @ [1024,1024] -> f32 out
    gemm_abt<<<512, 256, 0, stream>>>(attn, WoutT, b_out, out,
                                      BATCH * SEQ, DM, DM);
}